// Round 1
// 468.822 us; speedup vs baseline: 1.0210x; 1.0210x over previous
//
#include <hip/hip_runtime.h>
#include <math.h>

// Problem constants
#define BATCH  4
#define LSEQ   2048
#define DMODEL 1024
#define MROWS  (BATCH * LSEQ)   // 8192
#define SCORE_SCALE 8.0f        // sqrt(1024/16), reference MULTIPLIES

#define THREEFRY_PARTITIONABLE 1  // verified correct in round 1

typedef __bf16 bf16_t;
typedef bf16_t bf16x8 __attribute__((ext_vector_type(8)));
typedef bf16_t bf16x4 __attribute__((ext_vector_type(4)));
typedef float  f32x4  __attribute__((ext_vector_type(4)));

#define LDSP(p) ((__attribute__((address_space(3))) void*)(p))
#define GLBP(p) ((const __attribute__((address_space(1))) void*)(p))

// ---------------------------------------------------------------------------
// threefry dropout (verified round 1)
// ---------------------------------------------------------------------------
__device__ __forceinline__ unsigned rotl32(unsigned x, int r) {
    return (x << r) | (x >> (32 - r));
}

__device__ __forceinline__ void threefry2x32(unsigned k0, unsigned k1,
                                             unsigned x0, unsigned x1,
                                             unsigned& o0, unsigned& o1) {
    const unsigned ks0 = k0, ks1 = k1, ks2 = k0 ^ k1 ^ 0x1BD11BDAu;
    x0 += ks0; x1 += ks1;
#define TF_R(r) { x0 += x1; x1 = rotl32(x1, r); x1 ^= x0; }
    TF_R(13) TF_R(15) TF_R(26) TF_R(6)
    x0 += ks1; x1 += ks2 + 1u;
    TF_R(17) TF_R(29) TF_R(16) TF_R(24)
    x0 += ks2; x1 += ks0 + 2u;
    TF_R(13) TF_R(15) TF_R(26) TF_R(6)
    x0 += ks0; x1 += ks1 + 3u;
    TF_R(17) TF_R(29) TF_R(16) TF_R(24)
    x0 += ks1; x1 += ks2 + 4u;
    TF_R(13) TF_R(15) TF_R(26) TF_R(6)
    x0 += ks2; x1 += ks0 + 5u;
#undef TF_R
    o0 = x0; o1 = x1;
}

__device__ __forceinline__ bool dropout_keep(unsigned n) {
    unsigned o0, o1;
#if THREEFRY_PARTITIONABLE
    threefry2x32(0u, 42u, 0u, n, o0, o1);
    unsigned bits = o0 ^ o1;
#else
    const unsigned HALF = (unsigned)(BATCH * LSEQ) * (unsigned)LSEQ / 2u;
    unsigned c0 = (n < HALF) ? n : (n - HALF);
    unsigned c1 = (n < HALF) ? (n + HALF) : n;
    threefry2x32(0u, 42u, c0, c1, o0, o1);
    unsigned bits = (n < HALF) ? o0 : o1;
#endif
    return bits < 0x80000000u;
}

// ---------------------------------------------------------------------------
// Split fp32 -> bf16 hi/lo. grid.y selects input (X0/X1), output offset y*n.
// ---------------------------------------------------------------------------
__global__ __launch_bounds__(256)
void split_f32(const float* __restrict__ X0, const float* __restrict__ X1,
               bf16_t* __restrict__ hi, bf16_t* __restrict__ lo, int n) {
    const int y = blockIdx.y;
    const float* X = y ? X1 : X0;
    long long i = (long long)(blockIdx.x * 256 + threadIdx.x) * 4;
    if (i >= n) return;
    float4 v = *(const float4*)(X + i);
    bf16x4 h, l;
    h[0] = (bf16_t)v.x; l[0] = (bf16_t)(v.x - (float)h[0]);
    h[1] = (bf16_t)v.y; l[1] = (bf16_t)(v.y - (float)h[1]);
    h[2] = (bf16_t)v.z; l[2] = (bf16_t)(v.z - (float)h[2]);
    h[3] = (bf16_t)v.w; l[3] = (bf16_t)(v.w - (float)h[3]);
    *(bf16x4*)(hi + (long long)y * n + i) = h;
    *(bf16x4*)(lo + (long long)y * n + i) = l;
}

// plain fp32 -> bf16 convert (V path needs only hi plane)
__global__ __launch_bounds__(256)
void cvt_bf16(const float* __restrict__ X, bf16_t* __restrict__ Y, int n) {
    long long i = (long long)(blockIdx.x * 256 + threadIdx.x) * 8;
    if (i >= n) return;
    float4 a = *(const float4*)(X + i);
    float4 b = *(const float4*)(X + i + 4);
    bf16x8 o;
    o[0] = (bf16_t)a.x; o[1] = (bf16_t)a.y; o[2] = (bf16_t)a.z; o[3] = (bf16_t)a.w;
    o[4] = (bf16_t)b.x; o[5] = (bf16_t)b.y; o[6] = (bf16_t)b.z; o[7] = (bf16_t)b.w;
    *(bf16x8*)(Y + i) = o;
}

// W fp32 [K][N] -> W^T hi/lo bf16 [N][K]; grid.z selects W0/W1, out += z*K*N
__global__ __launch_bounds__(256)
void split_transpose(const float* __restrict__ W0, const float* __restrict__ W1,
                     bf16_t* __restrict__ Th, bf16_t* __restrict__ Tl,
                     int Kd, int Nd) {
    __shared__ float t[32][33];
    const int z = blockIdx.z;
    const float* W = z ? W1 : W0;
    const long long zo = (long long)z * Kd * Nd;
    const int bx = blockIdx.x * 32;  // n
    const int by = blockIdx.y * 32;  // k
    const int tx = threadIdx.x & 31, ty = threadIdx.x >> 5;  // 32x8
#pragma unroll
    for (int i = 0; i < 4; ++i)
        t[ty + i * 8][tx] = W[(long long)(by + ty + i * 8) * Nd + bx + tx];
    __syncthreads();
#pragma unroll
    for (int i = 0; i < 4; ++i) {
        float v = t[tx][ty + i * 8];
        long long idx = zo + (long long)(bx + ty + i * 8) * Kd + by + tx;
        bf16_t h = (bf16_t)v;
        Th[idx] = h;
        Tl[idx] = (bf16_t)(v - (float)h);
    }
}

// ---------------------------------------------------------------------------
// MFMA GEMM (128x128, plain bf16 paths: V^T and PV). Unchanged from r5.
// ---------------------------------------------------------------------------
template <int SPLIT, int OUT, int BROW>
__global__ __launch_bounds__(256)
void gemm_mfma(const bf16_t* __restrict__ Ah, const bf16_t* __restrict__ Al,
               const bf16_t* __restrict__ Bh, const bf16_t* __restrict__ Bl,
               const float* __restrict__ bias, const float* __restrict__ bias2,
               float* __restrict__ Cf, bf16_t* __restrict__ Ch,
               bf16_t* __restrict__ Cl,
               int M, int N, int K, float scale,
               long long sA, long long sB, long long sC,
               int SX, int NYt) {
    constexpr int TM = 128, TN = 128, TOT = 256, CHUNKS = 4;
    constexpr int NB = SPLIT ? 2 : 1;
    constexpr int BUFSZ = NB * TOT * 32;
    __shared__ __align__(16) bf16_t smem[2 * BUFSZ];

    // --- XCD-aware tile mapping (1D grid) ---
    const int bid = blockIdx.x;
    const int xcd = bid & 7;
    const int ii = bid >> 3;
    const int perz = SX * NYt;
    const int zz = ii / perz;
    const int rr = ii - zz * perz;
    const int nx = xcd + ((rr % SX) << 3);
    const int my = rr / SX;
    const long long z = zz;
    const int m0 = my * TM, n0 = nx * TN;

    const int tid = threadIdx.x;
    const int lane = tid & 63;
    const int wave = tid >> 6;
    const int quad = lane >> 4;
    const int l16 = lane & 15;
    const int wm = (wave & 1) * 64;
    const int wn = (wave >> 1) * 64;

    const bf16_t* gAh = Ah + z * sA;
    const bf16_t* gBh = Bh + z * sB;
    const bf16_t* gAl = SPLIT ? Al + z * sA : nullptr;
    const bf16_t* gBl = SPLIT ? Bl + z * sB : nullptr;

    // staging lane geometry: 16 rows x 4 column-groups of 16B per chunk
    const int lrow = lane >> 2;                               // 0..15
    const int scol = ((lane & 3) ^ ((lrow >> 1) & 3)) * 8;    // swizzled col
    const int sw = (l16 >> 1) & 3;                            // read swizzle

    auto issue = [&](int k0, int b) {
        bf16_t* base = smem + b * BUFSZ;
#pragma unroll
        for (int c = 0; c < CHUNKS; ++c) {
            const int rbase = wave * 64 + c * 16;
            const int row = rbase + lrow;
            if (rbase < TM) {
                const long long g = (long long)(m0 + row) * K + k0 + scol;
                __builtin_amdgcn_global_load_lds(GLBP(gAh + g), LDSP(base + row * 32), 16, 0, 0);
                if constexpr (SPLIT)
                    __builtin_amdgcn_global_load_lds(GLBP(gAl + g), LDSP(base + TOT * 32 + row * 32), 16, 0, 0);
            } else {
                const int br = row - TM;
                const long long g = (long long)(n0 + br) * K + k0 + scol;
                __builtin_amdgcn_global_load_lds(GLBP(gBh + g), LDSP(base + TM * 32 + br * 32), 16, 0, 0);
                if constexpr (SPLIT)
                    __builtin_amdgcn_global_load_lds(GLBP(gBl + g), LDSP(base + TOT * 32 + TM * 32 + br * 32), 16, 0, 0);
            }
        }
    };

    f32x4 acc[4][4];
#pragma unroll
    for (int i = 0; i < 4; ++i)
#pragma unroll
        for (int j = 0; j < 4; ++j)
            acc[i][j] = (f32x4){0.f, 0.f, 0.f, 0.f};

    issue(0, 0);
    const int NIT = K >> 5;
    for (int it = 0; it < NIT; ++it) {
        const int b = it & 1;
        const bool more = (it + 1) < NIT;
        if (more) issue((it + 1) << 5, b ^ 1);
        if constexpr (SPLIT) {
            if (more) asm volatile("s_waitcnt vmcnt(8)" ::: "memory");
            else      asm volatile("s_waitcnt vmcnt(0)" ::: "memory");
        } else {
            if (more) asm volatile("s_waitcnt vmcnt(4)" ::: "memory");
            else      asm volatile("s_waitcnt vmcnt(0)" ::: "memory");
        }
        asm volatile("s_barrier" ::: "memory");

        bf16_t* base = smem + b * BUFSZ;
        bf16_t* sAh = base;
        bf16_t* sBh = base + TM * 32;
        bf16_t* sAl = base + TOT * 32;
        bf16_t* sBl = base + TOT * 32 + TM * 32;

        bf16x8 afh[4], bfh[4], afl[4], bfl[4];
#pragma unroll
        for (int i = 0; i < 4; ++i) {
            const int ao = (wm + i * 16 + l16) * 32 + (quad ^ sw) * 8;
            afh[i] = *(const bf16x8*)(sAh + ao);
            if constexpr (SPLIT) afl[i] = *(const bf16x8*)(sAl + ao);
        }
#pragma unroll
        for (int j = 0; j < 4; ++j) {
            const int bo = (wn + j * 16 + l16) * 32 + (quad ^ sw) * 8;
            bfh[j] = *(const bf16x8*)(sBh + bo);
            if constexpr (SPLIT) bfl[j] = *(const bf16x8*)(sBl + bo);
        }
#pragma unroll
        for (int i = 0; i < 4; ++i)
#pragma unroll
            for (int j = 0; j < 4; ++j) {
                acc[i][j] = __builtin_amdgcn_mfma_f32_16x16x32_bf16(afh[i], bfh[j], acc[i][j], 0, 0, 0);
                if constexpr (SPLIT) {
                    acc[i][j] = __builtin_amdgcn_mfma_f32_16x16x32_bf16(afh[i], bfl[j], acc[i][j], 0, 0, 0);
                    acc[i][j] = __builtin_amdgcn_mfma_f32_16x16x32_bf16(afl[i], bfh[j], acc[i][j], 0, 0, 0);
                }
            }
        asm volatile("s_barrier" ::: "memory");
    }

    const float* bz = (z == 1 && bias2) ? bias2 : bias;
#pragma unroll
    for (int i = 0; i < 4; ++i)
#pragma unroll
        for (int j = 0; j < 4; ++j) {
            const int n = n0 + wn + j * 16 + l16;
            float bvn = 0.f;
            if constexpr (OUT != 0 && !BROW) bvn = bz[n];
#pragma unroll
            for (int r = 0; r < 4; ++r) {
                const int m = m0 + wm + i * 16 + quad * 4 + r;
                const long long idx = z * sC + (long long)m * N + n;
                float v = acc[i][j][r];
                if constexpr (OUT == 0) {
                    Cf[idx] = v * scale;
                } else if constexpr (OUT == 1) {
                    v += bvn;
                    bf16_t h = (bf16_t)v;
                    Ch[idx] = h;
                    Cl[idx] = (bf16_t)(v - (float)h);
                } else {
                    v += BROW ? bz[m] : bvn;
                    Ch[idx] = (bf16_t)v;
                }
            }
        }
}

// ---------------------------------------------------------------------------
// NEW r6: 256x256-tile 4-phase split GEMM (8-phase-family schedule, T3+T4+T5).
// 512 threads (8 waves, 2Mx4N), BK=32, per-wave output 128x64 (acc[8][4]).
// LDS: 4 planes (Ah,Bh,Al,Bl) x 256x32 bf16 x 2 buffers = 128 KB.
// Staging: all 8 global_load_lds/wave at tile top, counted vmcnt(8) (full-tile
// prefetch window, never drains to 0 mid-loop). Phases: per 2 A-subrows,
// {ds_read; s_barrier; lgkmcnt(0); sched_barrier; setprio(1) 24 MFMA setprio(0);
//  s_barrier} -- the lockstep role-split that makes setprio pay (T5 gate).
// Same verified XOR col-group swizzle as the 128^2 kernel (0 bank conflicts).
// Grid: exactly 256 blocks, 1 block/CU. XCD-contiguous mapping (nx slowest).
// OUT: 0 = fp32*scale (S=QK^T), 1 = bf16 hi/lo + bias (projections, bias2=z1).
// ---------------------------------------------------------------------------
template <int OUT>
__global__ __launch_bounds__(512, 2)
void gemm_mfma_8ph(const bf16_t* __restrict__ Ah, const bf16_t* __restrict__ Al,
                   const bf16_t* __restrict__ Bh, const bf16_t* __restrict__ Bl,
                   const float* __restrict__ bias, const float* __restrict__ bias2,
                   float* __restrict__ Cf, bf16_t* __restrict__ Ch,
                   bf16_t* __restrict__ Cl,
                   int M, int N, int K, float scale,
                   long long sA, long long sB, long long sC,
                   int NYt, int NZ) {
    constexpr int TM = 256, TN = 256;
    constexpr int PLANE = 256 * 32;               // elements per plane (16 KB)
    __shared__ __align__(16) bf16_t smem[2 * 4 * PLANE];  // 128 KB

    // --- XCD-contiguous tile mapping: gid ordered (nx, z, my), nx slowest ---
    const int bid = blockIdx.x;
    const int gid = (bid & 7) * 32 + (bid >> 3);   // 256 blocks total
    const int nzy = NZ * NYt;
    const int nx = gid / nzy;
    const int rem = gid - nx * nzy;
    const int zz = rem / NYt;
    const int my = rem - zz * NYt;
    const long long z = zz;
    const int m0 = my * TM, n0 = nx * TN;

    const int tid = threadIdx.x;
    const int lane = tid & 63;
    const int wave = tid >> 6;          // 0..7
    const int quad = lane >> 4;
    const int l16 = lane & 15;
    const int wm = (wave >> 2) * 128;   // 0,128
    const int wn = (wave & 3) * 64;     // 0,64,128,192

    const bf16_t* gAh = Ah + z * sA;
    const bf16_t* gAl = Al + z * sA;
    const bf16_t* gBh = Bh + z * sB;
    const bf16_t* gBl = Bl + z * sB;

    // staging lane geometry (identical swizzle scheme to 128^2 kernel)
    const int lrow = lane >> 2;                               // 0..15
    const int scol = ((lane & 3) ^ ((lrow >> 1) & 3)) * 8;    // swizzled col
    const int sw = (l16 >> 1) & 3;                            // read swizzle

    // 64 wave-issues cover 4 planes x 256 rows, 16 rows per issue.
    // s = wave*8+c: plane = s>>4 (wave-uniform), rowbase = (s&15)*16.
    auto issue = [&](int k0, int b) {
        bf16_t* base = smem + b * (4 * PLANE);
#pragma unroll
        for (int c = 0; c < 8; ++c) {
            const int s = wave * 8 + c;
            const int p = s >> 4;                      // 0:Ah 1:Bh 2:Al 3:Bl
            const int row = ((s & 15) << 4) + lrow;    // 0..255
            bf16_t* dst = base + p * PLANE + row * 32; // linear dest (lane*16B)
            const long long ka = (long long)(m0 + row) * K + k0 + scol;
            const long long kb = (long long)(n0 + row) * K + k0 + scol;
            if (p == 0)
                __builtin_amdgcn_global_load_lds(GLBP(gAh + ka), LDSP(dst), 16, 0, 0);
            else if (p == 1)
                __builtin_amdgcn_global_load_lds(GLBP(gBh + kb), LDSP(dst), 16, 0, 0);
            else if (p == 2)
                __builtin_amdgcn_global_load_lds(GLBP(gAl + ka), LDSP(dst), 16, 0, 0);
            else
                __builtin_amdgcn_global_load_lds(GLBP(gBl + kb), LDSP(dst), 16, 0, 0);
        }
    };

    f32x4 acc[8][4];
#pragma unroll
    for (int i = 0; i < 8; ++i)
#pragma unroll
        for (int j = 0; j < 4; ++j)
            acc[i][j] = (f32x4){0.f, 0.f, 0.f, 0.f};

    issue(0, 0);
    const int NIT = K >> 5;   // 32
    for (int it = 0; it < NIT; ++it) {
        const int b = it & 1;
        const bool more = (it + 1) < NIT;
        if (more) issue((it + 1) << 5, b ^ 1);
        // counted wait: the 8 oldest (this tile's buffer) land; next tile's
        // 8 stay in flight across the whole tile's compute (T4).
        if (more) asm volatile("s_waitcnt vmcnt(8)" ::: "memory");
        else      asm volatile("s_waitcnt vmcnt(0)" ::: "memory");
        asm volatile("s_barrier" ::: "memory");

        bf16_t* base = smem + b * (4 * PLANE);
        bf16_t* sAh = base;
        bf16_t* sBh = base + PLANE;
        bf16_t* sAl = base + 2 * PLANE;
        bf16_t* sBl = base + 3 * PLANE;

        // B fragments for this wave's 64-col stripe (read once per K-tile)
        bf16x8 bfh[4], bfl[4];
#pragma unroll
        for (int j = 0; j < 4; ++j) {
            const int bo = (wn + j * 16 + l16) * 32 + (quad ^ sw) * 8;
            bfh[j] = *(const bf16x8*)(sBh + bo);
            bfl[j] = *(const bf16x8*)(sBl + bo);
        }

#pragma unroll
        for (int ph = 0; ph < 4; ++ph) {
            bf16x8 afh[2], afl[2];
#pragma unroll
            for (int i = 0; i < 2; ++i) {
                const int ao = (wm + (ph * 2 + i) * 16 + l16) * 32 + (quad ^ sw) * 8;
                afh[i] = *(const bf16x8*)(sAh + ao);
                afl[i] = *(const bf16x8*)(sAl + ao);
            }
            asm volatile("s_barrier" ::: "memory");
            asm volatile("s_waitcnt lgkmcnt(0)" ::: "memory");
            __builtin_amdgcn_sched_barrier(0);
            __builtin_amdgcn_s_setprio(1);
#pragma unroll
            for (int i = 0; i < 2; ++i)
#pragma unroll
                for (int j = 0; j < 4; ++j) {
                    f32x4 a = acc[ph * 2 + i][j];
                    a = __builtin_amdgcn_mfma_f32_16x16x32_bf16(afh[i], bfh[j], a, 0, 0, 0);
                    a = __builtin_amdgcn_mfma_f32_16x16x32_bf16(afh[i], bfl[j], a, 0, 0, 0);
                    a = __builtin_amdgcn_mfma_f32_16x16x32_bf16(afl[i], bfh[j], a, 0, 0, 0);
                    acc[ph * 2 + i][j] = a;
                }
            __builtin_amdgcn_s_setprio(0);
            asm volatile("s_barrier" ::: "memory");
        }
    }

    const float* bz = (z == 1 && bias2) ? bias2 : bias;
#pragma unroll
    for (int i = 0; i < 8; ++i)
#pragma unroll
        for (int j = 0; j < 4; ++j) {
            const int n = n0 + wn + j * 16 + l16;
            float bvn = 0.f;
            if constexpr (OUT != 0) bvn = bz[n];
#pragma unroll
            for (int r = 0; r < 4; ++r) {
                const int m = m0 + wm + i * 16 + quad * 4 + r;
                const long long idx = z * sC + (long long)m * N + n;
                float v = acc[i][j][r];
                if constexpr (OUT == 0) {
                    Cf[idx] = v * scale;
                } else {
                    v += bvn;
                    bf16_t h = (bf16_t)v;
                    Ch[idx] = h;
                    Cl[idx] = (bf16_t)(v - (float)h);
                }
            }
        }
}

// ---------------------------------------------------------------------------
// Row softmax + dropout, register-resident (r5, verified): S fp32 -> P bf16.
// ---------------------------------------------------------------------------
__global__ __launch_bounds__(256)
void softmax_dropout(const float* __restrict__ S, bf16_t* __restrict__ P) {
    const unsigned row = blockIdx.x;
    const float* rp = S + (long long)row * LSEQ;
    const int tid = threadIdx.x;

    float v[8];
    *(float4*)(v)     = *(const float4*)(rp + tid * 8);
    *(float4*)(v + 4) = *(const float4*)(rp + tid * 8 + 4);

    float m = v[0];
#pragma unroll
    for (int e = 1; e < 8; ++e) m = fmaxf(m, v[e]);
#pragma unroll
    for (int o = 1; o < 64; o <<= 1) m = fmaxf(m, __shfl_xor(m, o));
    __shared__ float redm[4];
    if ((tid & 63) == 0) redm[tid >> 6] = m;
    __syncthreads();
    m = fmaxf(fmaxf(redm[0], redm[1]), fmaxf(redm[2], redm[3]));

    float s = 0.f;
#pragma unroll
    for (int e = 0; e < 8; ++e) { v[e] = __expf(v[e] - m); s += v[e]; }
#pragma unroll
    for (int o = 1; o < 64; o <<= 1) s += __shfl_xor(s, o);
    __shared__ float reds[4];
    if ((tid & 63) == 0) reds[tid >> 6] = s;
    __syncthreads();
    s = (reds[0] + reds[1]) + (reds[2] + reds[3]);

    const float inv = 2.0f / s;  // dropout /0.5 folded in
    const unsigned nb = row * (unsigned)LSEQ + (unsigned)(tid * 8);
    bf16x8 o8;
#pragma unroll
    for (int e = 0; e < 8; ++e)
        o8[e] = (bf16_t)(dropout_keep(nb + e) ? v[e] * inv : 0.0f);
    *(bf16x8*)(P + (long long)row * LSEQ + tid * 8) = o8;
}

// ---------------------------------------------------------------------------
extern "C" void kernel_launch(void* const* d_in, const int* in_sizes, int n_in,
                              void* d_out, int out_size, void* d_ws, size_t ws_size,
                              hipStream_t stream) {
    const float* query = (const float*)d_in[0];
    const float* key_  = (const float*)d_in[1];
    const float* value = (const float*)d_in[2];
    const float* Wq = (const float*)d_in[3];
    const float* bq = (const float*)d_in[4];
    const float* Wk = (const float*)d_in[5];
    const float* bk = (const float*)d_in[6];
    const float* Wv = (const float*)d_in[7];
    const float* bv = (const float*)d_in[8];
    float* out = (float*)d_out;

    // ws layout (bytes), Q1 = 8192*1024*2 = 16.78MB; total 9*Q1 + 8.4MB = 159.4MB
    char* w = (char*)d_ws;
    const size_t Q1 = (size_t)MROWS * DMODEL * 2;
    bf16_t* Qh  = (bf16_t*)(w);               // [0,2Q1): Qh,Kh  (z-stride NELEM)
    bf16_t* Ql  = (bf16_t*)(w + 2 * Q1);      // [2Q1,4Q1): Ql,Kl
    bf16_t* VT  = (bf16_t*)(w + 4 * Q1);      // [4Q1,5Q1): V^T per batch [D][LK]
    float*  S   = (float*)(w + 5 * Q1);       // [5Q1,9Q1) fp32 scores
    // phase-A aliases inside S region:
    bf16_t* XvH  = (bf16_t*)(w + 5 * Q1);     // V bf16 (hi only)
    bf16_t* XqkH = (bf16_t*)(w + 5 * Q1);     // QK split hi (z-stride NELEM)
    bf16_t* XqkL = (bf16_t*)(w + 7 * Q1);     // QK split lo (z-stride NELEM)
    bf16_t* WTh = (bf16_t*)(w + 9 * Q1);      // 2 z-slots of D*D
    bf16_t* WTl = (bf16_t*)(w + 9 * Q1 + 2 * (size_t)DMODEL * DMODEL * 2);
    bf16_t* P   = Qh;  // [0,2Q1) aliases Qh+Kh (dead after QK^T)

    dim3 b256(256);
    dim3 b512(512);
    const int NELEM = MROWS * DMODEL;
    const long long DD = (long long)DMODEL * DMODEL;
    dim3 gwt1(DMODEL / 32, DMODEL / 32, 1);
    dim3 gwt2(DMODEL / 32, DMODEL / 32, 2);

    // --- V path: V^T = Wv^T @ Xv^T directly (plain bf16, row-bias)
    // grid: NX=LSEQ/128=16, NY=DMODEL/128=8, NZ=4 -> 512 blocks, SX=2
    split_transpose<<<gwt1, b256, 0, stream>>>(Wv, nullptr, WTh, WTl, DMODEL, DMODEL);
    cvt_bf16<<<dim3(NELEM / 2048), b256, 0, stream>>>(value, XvH, NELEM);
    gemm_mfma<0, 2, 1><<<dim3(512), b256, 0, stream>>>(
        WTh, nullptr, XvH, nullptr, bv, nullptr, nullptr, VT, nullptr,
        DMODEL, LSEQ, DMODEL, 1.f,
        0, (long long)LSEQ * DMODEL, (long long)DMODEL * LSEQ,
        2, DMODEL / 128);

    // --- Q and K projections, fused over z (8-phase 256^2 split kernel)
    // grid: NXt=4, NYt=32, NZ=2 -> 256 blocks, 1 block/CU
    split_transpose<<<gwt2, b256, 0, stream>>>(Wq, Wk, WTh, WTl, DMODEL, DMODEL);
    split_f32<<<dim3(NELEM / 1024, 2), b256, 0, stream>>>(query, key_, XqkH, XqkL, NELEM);
    gemm_mfma_8ph<1><<<dim3(256), b512, 0, stream>>>(
        XqkH, XqkL, WTh, WTl, bq, bk, nullptr, Qh, Ql,
        MROWS, DMODEL, DMODEL, 1.f,
        (long long)NELEM, DD, (long long)NELEM,
        MROWS / 256, 2);

    // --- S = 8 * Q K^T (batched, 8-phase 256^2 split kernel)
    // grid: NXt=8, NYt=8, NZ=4 -> 256 blocks, 1 block/CU
    gemm_mfma_8ph<0><<<dim3(256), b512, 0, stream>>>(
        Qh, Ql, Qh + NELEM, Ql + NELEM, nullptr, nullptr, S, nullptr, nullptr,
        LSEQ, LSEQ, DMODEL, SCORE_SCALE,
        (long long)LSEQ * DMODEL, (long long)LSEQ * DMODEL,
        (long long)LSEQ * LSEQ,
        LSEQ / 256, 4);

    // --- softmax + dropout -> P bf16 (aliases Qh/Kh region)
    softmax_dropout<<<dim3(MROWS), b256, 0, stream>>>(S, P);

    // --- O = P V (plain bf16), B operand = V^T [D][LK] per batch
    // grid: NX=8, NY=16, NZ=4 -> 512 blocks, SX=1
    gemm_mfma<0, 0, 0><<<dim3(512), b256, 0, stream>>>(
        P, nullptr, VT, nullptr, nullptr, nullptr, out, nullptr, nullptr,
        LSEQ, DMODEL, LSEQ, 1.f,
        (long long)LSEQ * LSEQ, (long long)DMODEL * LSEQ,
        (long long)LSEQ * DMODEL,
        1, LSEQ / 128);
}

// Round 3
// 453.057 us; speedup vs baseline: 1.0566x; 1.0348x over previous
//
#include <hip/hip_runtime.h>
#include <math.h>

// Problem constants
#define BATCH  4
#define LSEQ   2048
#define DMODEL 1024
#define MROWS  (BATCH * LSEQ)   // 8192
#define SCORE_SCALE 8.0f        // sqrt(1024/16), reference MULTIPLIES

#define THREEFRY_PARTITIONABLE 1  // verified correct in round 1

typedef __bf16 bf16_t;
typedef bf16_t bf16x8 __attribute__((ext_vector_type(8)));
typedef bf16_t bf16x4 __attribute__((ext_vector_type(4)));
typedef float  f32x4  __attribute__((ext_vector_type(4)));

#define LDSP(p) ((__attribute__((address_space(3))) void*)(p))
#define GLBP(p) ((const __attribute__((address_space(1))) void*)(p))

// ---------------------------------------------------------------------------
// threefry dropout (verified round 1)
// ---------------------------------------------------------------------------
__device__ __forceinline__ unsigned rotl32(unsigned x, int r) {
    return (x << r) | (x >> (32 - r));
}

__device__ __forceinline__ void threefry2x32(unsigned k0, unsigned k1,
                                             unsigned x0, unsigned x1,
                                             unsigned& o0, unsigned& o1) {
    const unsigned ks0 = k0, ks1 = k1, ks2 = k0 ^ k1 ^ 0x1BD11BDAu;
    x0 += ks0; x1 += ks1;
#define TF_R(r) { x0 += x1; x1 = rotl32(x1, r); x1 ^= x0; }
    TF_R(13) TF_R(15) TF_R(26) TF_R(6)
    x0 += ks1; x1 += ks2 + 1u;
    TF_R(17) TF_R(29) TF_R(16) TF_R(24)
    x0 += ks2; x1 += ks0 + 2u;
    TF_R(13) TF_R(15) TF_R(26) TF_R(6)
    x0 += ks0; x1 += ks1 + 3u;
    TF_R(17) TF_R(29) TF_R(16) TF_R(24)
    x0 += ks1; x1 += ks2 + 4u;
    TF_R(13) TF_R(15) TF_R(26) TF_R(6)
    x0 += ks2; x1 += ks0 + 5u;
#undef TF_R
    o0 = x0; o1 = x1;
}

__device__ __forceinline__ bool dropout_keep(unsigned n) {
    unsigned o0, o1;
#if THREEFRY_PARTITIONABLE
    threefry2x32(0u, 42u, 0u, n, o0, o1);
    unsigned bits = o0 ^ o1;
#else
    const unsigned HALF = (unsigned)(BATCH * LSEQ) * (unsigned)LSEQ / 2u;
    unsigned c0 = (n < HALF) ? n : (n - HALF);
    unsigned c1 = (n < HALF) ? (n + HALF) : n;
    threefry2x32(0u, 42u, c0, c1, o0, o1);
    unsigned bits = (n < HALF) ? o0 : o1;
#endif
    return bits < 0x80000000u;
}

// ---------------------------------------------------------------------------
// Split fp32 -> bf16 hi/lo. grid.y selects input (X0/X1), output offset y*n.
// ---------------------------------------------------------------------------
__global__ __launch_bounds__(256)
void split_f32(const float* __restrict__ X0, const float* __restrict__ X1,
               bf16_t* __restrict__ hi, bf16_t* __restrict__ lo, int n) {
    const int y = blockIdx.y;
    const float* X = y ? X1 : X0;
    long long i = (long long)(blockIdx.x * 256 + threadIdx.x) * 4;
    if (i >= n) return;
    float4 v = *(const float4*)(X + i);
    bf16x4 h, l;
    h[0] = (bf16_t)v.x; l[0] = (bf16_t)(v.x - (float)h[0]);
    h[1] = (bf16_t)v.y; l[1] = (bf16_t)(v.y - (float)h[1]);
    h[2] = (bf16_t)v.z; l[2] = (bf16_t)(v.z - (float)h[2]);
    h[3] = (bf16_t)v.w; l[3] = (bf16_t)(v.w - (float)h[3]);
    *(bf16x4*)(hi + (long long)y * n + i) = h;
    *(bf16x4*)(lo + (long long)y * n + i) = l;
}

// plain fp32 -> bf16 convert (V path needs only hi plane)
__global__ __launch_bounds__(256)
void cvt_bf16(const float* __restrict__ X, bf16_t* __restrict__ Y, int n) {
    long long i = (long long)(blockIdx.x * 256 + threadIdx.x) * 8;
    if (i >= n) return;
    float4 a = *(const float4*)(X + i);
    float4 b = *(const float4*)(X + i + 4);
    bf16x8 o;
    o[0] = (bf16_t)a.x; o[1] = (bf16_t)a.y; o[2] = (bf16_t)a.z; o[3] = (bf16_t)a.w;
    o[4] = (bf16_t)b.x; o[5] = (bf16_t)b.y; o[6] = (bf16_t)b.z; o[7] = (bf16_t)b.w;
    *(bf16x8*)(Y + i) = o;
}

// W fp32 [K][N] -> W^T hi/lo bf16 [N][K]; grid.z selects W0/W1, out += z*K*N
__global__ __launch_bounds__(256)
void split_transpose(const float* __restrict__ W0, const float* __restrict__ W1,
                     bf16_t* __restrict__ Th, bf16_t* __restrict__ Tl,
                     int Kd, int Nd) {
    __shared__ float t[32][33];
    const int z = blockIdx.z;
    const float* W = z ? W1 : W0;
    const long long zo = (long long)z * Kd * Nd;
    const int bx = blockIdx.x * 32;  // n
    const int by = blockIdx.y * 32;  // k
    const int tx = threadIdx.x & 31, ty = threadIdx.x >> 5;  // 32x8
#pragma unroll
    for (int i = 0; i < 4; ++i)
        t[ty + i * 8][tx] = W[(long long)(by + ty + i * 8) * Nd + bx + tx];
    __syncthreads();
#pragma unroll
    for (int i = 0; i < 4; ++i) {
        float v = t[tx][ty + i * 8];
        long long idx = zo + (long long)(bx + ty + i * 8) * Kd + by + tx;
        bf16_t h = (bf16_t)v;
        Th[idx] = h;
        Tl[idx] = (bf16_t)(v - (float)h);
    }
}

// ---------------------------------------------------------------------------
// MFMA GEMM (128x128, plain bf16 paths: V^T and PV). Unchanged from r5.
// ---------------------------------------------------------------------------
template <int SPLIT, int OUT, int BROW>
__global__ __launch_bounds__(256)
void gemm_mfma(const bf16_t* __restrict__ Ah, const bf16_t* __restrict__ Al,
               const bf16_t* __restrict__ Bh, const bf16_t* __restrict__ Bl,
               const float* __restrict__ bias, const float* __restrict__ bias2,
               float* __restrict__ Cf, bf16_t* __restrict__ Ch,
               bf16_t* __restrict__ Cl,
               int M, int N, int K, float scale,
               long long sA, long long sB, long long sC,
               int SX, int NYt) {
    constexpr int TM = 128, TN = 128, TOT = 256, CHUNKS = 4;
    constexpr int NB = SPLIT ? 2 : 1;
    constexpr int BUFSZ = NB * TOT * 32;
    __shared__ __align__(16) bf16_t smem[2 * BUFSZ];

    // --- XCD-aware tile mapping (1D grid) ---
    const int bid = blockIdx.x;
    const int xcd = bid & 7;
    const int ii = bid >> 3;
    const int perz = SX * NYt;
    const int zz = ii / perz;
    const int rr = ii - zz * perz;
    const int nx = xcd + ((rr % SX) << 3);
    const int my = rr / SX;
    const long long z = zz;
    const int m0 = my * TM, n0 = nx * TN;

    const int tid = threadIdx.x;
    const int lane = tid & 63;
    const int wave = tid >> 6;
    const int quad = lane >> 4;
    const int l16 = lane & 15;
    const int wm = (wave & 1) * 64;
    const int wn = (wave >> 1) * 64;

    const bf16_t* gAh = Ah + z * sA;
    const bf16_t* gBh = Bh + z * sB;
    const bf16_t* gAl = SPLIT ? Al + z * sA : nullptr;
    const bf16_t* gBl = SPLIT ? Bl + z * sB : nullptr;

    // staging lane geometry: 16 rows x 4 column-groups of 16B per chunk
    const int lrow = lane >> 2;                               // 0..15
    const int scol = ((lane & 3) ^ ((lrow >> 1) & 3)) * 8;    // swizzled col
    const int sw = (l16 >> 1) & 3;                            // read swizzle

    auto issue = [&](int k0, int b) {
        bf16_t* base = smem + b * BUFSZ;
#pragma unroll
        for (int c = 0; c < CHUNKS; ++c) {
            const int rbase = wave * 64 + c * 16;
            const int row = rbase + lrow;
            if (rbase < TM) {
                const long long g = (long long)(m0 + row) * K + k0 + scol;
                __builtin_amdgcn_global_load_lds(GLBP(gAh + g), LDSP(base + row * 32), 16, 0, 0);
                if constexpr (SPLIT)
                    __builtin_amdgcn_global_load_lds(GLBP(gAl + g), LDSP(base + TOT * 32 + row * 32), 16, 0, 0);
            } else {
                const int br = row - TM;
                const long long g = (long long)(n0 + br) * K + k0 + scol;
                __builtin_amdgcn_global_load_lds(GLBP(gBh + g), LDSP(base + TM * 32 + br * 32), 16, 0, 0);
                if constexpr (SPLIT)
                    __builtin_amdgcn_global_load_lds(GLBP(gBl + g), LDSP(base + TOT * 32 + TM * 32 + br * 32), 16, 0, 0);
            }
        }
    };

    f32x4 acc[4][4];
#pragma unroll
    for (int i = 0; i < 4; ++i)
#pragma unroll
        for (int j = 0; j < 4; ++j)
            acc[i][j] = (f32x4){0.f, 0.f, 0.f, 0.f};

    issue(0, 0);
    const int NIT = K >> 5;
    for (int it = 0; it < NIT; ++it) {
        const int b = it & 1;
        const bool more = (it + 1) < NIT;
        if (more) issue((it + 1) << 5, b ^ 1);
        if constexpr (SPLIT) {
            if (more) asm volatile("s_waitcnt vmcnt(8)" ::: "memory");
            else      asm volatile("s_waitcnt vmcnt(0)" ::: "memory");
        } else {
            if (more) asm volatile("s_waitcnt vmcnt(4)" ::: "memory");
            else      asm volatile("s_waitcnt vmcnt(0)" ::: "memory");
        }
        asm volatile("s_barrier" ::: "memory");

        bf16_t* base = smem + b * BUFSZ;
        bf16_t* sAh = base;
        bf16_t* sBh = base + TM * 32;
        bf16_t* sAl = base + TOT * 32;
        bf16_t* sBl = base + TOT * 32 + TM * 32;

        bf16x8 afh[4], bfh[4], afl[4], bfl[4];
#pragma unroll
        for (int i = 0; i < 4; ++i) {
            const int ao = (wm + i * 16 + l16) * 32 + (quad ^ sw) * 8;
            afh[i] = *(const bf16x8*)(sAh + ao);
            if constexpr (SPLIT) afl[i] = *(const bf16x8*)(sAl + ao);
        }
#pragma unroll
        for (int j = 0; j < 4; ++j) {
            const int bo = (wn + j * 16 + l16) * 32 + (quad ^ sw) * 8;
            bfh[j] = *(const bf16x8*)(sBh + bo);
            if constexpr (SPLIT) bfl[j] = *(const bf16x8*)(sBl + bo);
        }
#pragma unroll
        for (int i = 0; i < 4; ++i)
#pragma unroll
            for (int j = 0; j < 4; ++j) {
                acc[i][j] = __builtin_amdgcn_mfma_f32_16x16x32_bf16(afh[i], bfh[j], acc[i][j], 0, 0, 0);
                if constexpr (SPLIT) {
                    acc[i][j] = __builtin_amdgcn_mfma_f32_16x16x32_bf16(afh[i], bfl[j], acc[i][j], 0, 0, 0);
                    acc[i][j] = __builtin_amdgcn_mfma_f32_16x16x32_bf16(afl[i], bfh[j], acc[i][j], 0, 0, 0);
                }
            }
        asm volatile("s_barrier" ::: "memory");
    }

    const float* bz = (z == 1 && bias2) ? bias2 : bias;
#pragma unroll
    for (int i = 0; i < 4; ++i)
#pragma unroll
        for (int j = 0; j < 4; ++j) {
            const int n = n0 + wn + j * 16 + l16;
            float bvn = 0.f;
            if constexpr (OUT != 0 && !BROW) bvn = bz[n];
#pragma unroll
            for (int r = 0; r < 4; ++r) {
                const int m = m0 + wm + i * 16 + quad * 4 + r;
                const long long idx = z * sC + (long long)m * N + n;
                float v = acc[i][j][r];
                if constexpr (OUT == 0) {
                    Cf[idx] = v * scale;
                } else if constexpr (OUT == 1) {
                    v += bvn;
                    bf16_t h = (bf16_t)v;
                    Ch[idx] = h;
                    Cl[idx] = (bf16_t)(v - (float)h);
                } else {
                    v += BROW ? bz[m] : bvn;
                    Ch[idx] = (bf16_t)v;
                }
            }
        }
}

// ---------------------------------------------------------------------------
// r8: 256x256-tile split GEMM, m201-style 4-phase pipeline (T3+T4+T5).
// 512 threads (8 waves, 2Mx4N), BK=32, per-wave output 128x64 (acc[8][4]).
// LDS planes: 0=Ah 1=Al 2=Bh 3=Bl, each 256x32 bf16 (16KB); x2 buffers = 128KB.
//
// Staging: 8 rounds/K-tile (1 global_load_lds per wave per round):
//   rounds 0-3 = Bh(lo),Bh(hi),Bl(lo),Bl(hi)  -> needed at ph0
//   round  4+p = A-pair for phase p
// r7 BUG (NaN): vmcnt gate was at phase TOP, after the barrier -> wave A read
// LDS rows staged by wave B with only A's own loads drained (no guarantee B's
// landed; worst at it=0 where no barrier separated prologue from reads).
// r8 FIX: every vmcnt gate sits BEFORE the end-of-phase barrier that precedes
// the dependent reads (m201 rule: counted vmcnt, then barrier). Gates:
//   prologue-end & ph3-end: vmcnt(3)  -> rounds 0-4 of next tile visible
//   ph0-end: vmcnt(4) (round 5), ph1-end: vmcnt(5) (round 6),
//   ph2-end: vmcnt(6) (round 7); tail iter: 2/1/0.
// 3-6 loads stay in flight across every barrier; never 0 mid-loop.
// Same verified XOR col-group swizzle (row%16-keyed) -> 0 bank conflicts.
// Grid: exactly 256 blocks, 1 block/CU, XCD-contiguous mapping (nx slowest).
// OUT: 0 = fp32*scale (S=QK^T), 1 = bf16 hi/lo + bias (projections, bias2=z1).
// ---------------------------------------------------------------------------
template <int OUT>
__global__ __launch_bounds__(512, 2)
void gemm_mfma_8ph(const bf16_t* __restrict__ Ah, const bf16_t* __restrict__ Al,
                   const bf16_t* __restrict__ Bh, const bf16_t* __restrict__ Bl,
                   const float* __restrict__ bias, const float* __restrict__ bias2,
                   float* __restrict__ Cf, bf16_t* __restrict__ Ch,
                   bf16_t* __restrict__ Cl,
                   int M, int N, int K, float scale,
                   long long sA, long long sB, long long sC,
                   int NYt, int NZ) {
    constexpr int TM = 256, TN = 256;
    constexpr int PLANE = 256 * 32;               // elements per plane (16 KB)
    __shared__ __align__(16) bf16_t smem[2 * 4 * PLANE];  // 128 KB

    // --- XCD-contiguous tile mapping: gid ordered (nx, z, my), nx slowest ---
    const int bid = blockIdx.x;
    const int gid = (bid & 7) * 32 + (bid >> 3);   // 256 blocks total
    const int nzy = NZ * NYt;
    const int nx = gid / nzy;
    const int rem = gid - nx * nzy;
    const int zz = rem / NYt;
    const int my = rem - zz * NYt;
    const long long z = zz;
    const int m0 = my * TM, n0 = nx * TN;

    const int tid = threadIdx.x;
    const int lane = tid & 63;
    const int wave = tid >> 6;          // 0..7
    const int quad = lane >> 4;
    const int l16 = lane & 15;
    const int wm = (wave >> 2) * 128;   // 0,128
    const int wn = (wave & 3) * 64;     // 0,64,128,192

    const bf16_t* gAh = Ah + z * sA;
    const bf16_t* gAl = Al + z * sA;
    const bf16_t* gBh = Bh + z * sB;
    const bf16_t* gBl = Bl + z * sB;

    // staging lane geometry (verified swizzle: key = row % 16)
    const int lrow = lane >> 2;                               // 0..15
    const int scol = ((lane & 3) ^ ((lrow >> 1) & 3)) * 8;    // swizzled col
    const int sw = (l16 >> 1) & 3;                            // read swizzle

    // stage one round r (0..7) of K-tile at k0 into buffer b (1 issue/wave)
    auto stage_round = [&](int r, int k0, int b) {
        bf16_t* base = smem + b * (4 * PLANE);
        if (r < 4) {
            // B planes: r0 Bh rows 0-127, r1 Bh 128-255, r2 Bl 0-127, r3 Bl 128-255
            const int row = ((r & 1) << 7) + (wave << 4) + lrow;
            const bf16_t* src = (r >= 2) ? gBl : gBh;
            bf16_t* dst = base + ((r >= 2) ? 3 : 2) * PLANE + row * 32;
            __builtin_amdgcn_global_load_lds(
                GLBP(src + (long long)(n0 + row) * K + k0 + scol), LDSP(dst), 16, 0, 0);
        } else {
            // A pair for phase p: waves 0-3 -> Ah, 4-7 -> Al; rows {32p, 128+32p}
            const int p = r - 4;
            const int row = (p << 5) + ((wave & 2) ? 128 : 0) + ((wave & 1) << 4) + lrow;
            const bf16_t* src = (wave >= 4) ? gAl : gAh;
            bf16_t* dst = base + ((wave >= 4) ? 1 : 0) * PLANE + row * 32;
            __builtin_amdgcn_global_load_lds(
                GLBP(src + (long long)(m0 + row) * K + k0 + scol), LDSP(dst), 16, 0, 0);
        }
    };

    f32x4 acc[8][4];
#pragma unroll
    for (int i = 0; i < 8; ++i)
#pragma unroll
        for (int j = 0; j < 4; ++j)
            acc[i][j] = (f32x4){0.f, 0.f, 0.f, 0.f};

    // prologue: stage full first K-tile (8 rounds) into buf 0, then make
    // rounds 0-4 visible block-wide (vmcnt BEFORE barrier -- the r8 fix).
#pragma unroll
    for (int r = 0; r < 8; ++r) stage_round(r, 0, 0);
    asm volatile("s_waitcnt vmcnt(3)" ::: "memory");
    asm volatile("s_barrier" ::: "memory");

    const int NIT = K >> 5;   // 32
    for (int it = 0; it < NIT; ++it) {
        const int b = it & 1;
        const bool more = (it + 1) < NIT;
        const int k1 = (it + 1) << 5;
        bf16_t* base = smem + b * (4 * PLANE);
        bf16_t* sAh = base;
        bf16_t* sAl = base + PLANE;
        bf16_t* sBh = base + 2 * PLANE;
        bf16_t* sBl = base + 3 * PLANE;

        bf16x8 bfh[4], bfl[4];

#pragma unroll
        for (int ph = 0; ph < 4; ++ph) {
            // --- ds_read register subtile for this phase ---
            // (safe: previous end-barrier followed a vmcnt covering this data)
            bf16x8 afh[2], afl[2];
#pragma unroll
            for (int i = 0; i < 2; ++i) {
                const int ao = (wm + (ph * 2 + i) * 16 + l16) * 32 + (quad ^ sw) * 8;
                afh[i] = *(const bf16x8*)(sAh + ao);
                afl[i] = *(const bf16x8*)(sAl + ao);
            }
            if (ph == 0) {
#pragma unroll
                for (int j = 0; j < 4; ++j) {
                    const int bo = (wn + j * 16 + l16) * 32 + (quad ^ sw) * 8;
                    bfh[j] = *(const bf16x8*)(sBh + bo);
                    bfl[j] = *(const bf16x8*)(sBl + bo);
                }
            }

            // --- stage 2 rounds of next K-tile (fine interleave, T3) ---
            if (more) {
                stage_round(ph * 2,     k1, b ^ 1);
                stage_round(ph * 2 + 1, k1, b ^ 1);
            }

            if (ph == 0) asm volatile("s_waitcnt lgkmcnt(8)" ::: "memory");
            asm volatile("s_barrier" ::: "memory");
            asm volatile("s_waitcnt lgkmcnt(0)" ::: "memory");
            __builtin_amdgcn_sched_barrier(0);
            __builtin_amdgcn_s_setprio(1);
#pragma unroll
            for (int i = 0; i < 2; ++i)
#pragma unroll
                for (int j = 0; j < 4; ++j) {
                    f32x4 a = acc[ph * 2 + i][j];
                    a = __builtin_amdgcn_mfma_f32_16x16x32_bf16(afh[i], bfh[j], a, 0, 0, 0);
                    a = __builtin_amdgcn_mfma_f32_16x16x32_bf16(afh[i], bfl[j], a, 0, 0, 0);
                    a = __builtin_amdgcn_mfma_f32_16x16x32_bf16(afl[i], bfh[j], a, 0, 0, 0);
                    acc[ph * 2 + i][j] = a;
                }
            __builtin_amdgcn_s_setprio(0);

            // --- counted vmcnt gate for the NEXT phase's reads (before the
            //     end barrier -- this ordering is the r8 correctness fix) ---
            if (more) {
                if (ph == 0)      asm volatile("s_waitcnt vmcnt(4)" ::: "memory");
                else if (ph == 1) asm volatile("s_waitcnt vmcnt(5)" ::: "memory");
                else if (ph == 2) asm volatile("s_waitcnt vmcnt(6)" ::: "memory");
                else              asm volatile("s_waitcnt vmcnt(3)" ::: "memory");
            } else {
                if (ph == 0)      asm volatile("s_waitcnt vmcnt(2)" ::: "memory");
                else if (ph == 1) asm volatile("s_waitcnt vmcnt(1)" ::: "memory");
                else if (ph == 2) asm volatile("s_waitcnt vmcnt(0)" ::: "memory");
            }
            asm volatile("s_barrier" ::: "memory");
        }
    }

    const float* bz = (z == 1 && bias2) ? bias2 : bias;
#pragma unroll
    for (int i = 0; i < 8; ++i)
#pragma unroll
        for (int j = 0; j < 4; ++j) {
            const int n = n0 + wn + j * 16 + l16;
            float bvn = 0.f;
            if constexpr (OUT != 0) bvn = bz[n];
#pragma unroll
            for (int r = 0; r < 4; ++r) {
                const int m = m0 + wm + i * 16 + quad * 4 + r;
                const long long idx = z * sC + (long long)m * N + n;
                float v = acc[i][j][r];
                if constexpr (OUT == 0) {
                    Cf[idx] = v * scale;
                } else {
                    v += bvn;
                    bf16_t h = (bf16_t)v;
                    Ch[idx] = h;
                    Cl[idx] = (bf16_t)(v - (float)h);
                }
            }
        }
}

// ---------------------------------------------------------------------------
// Row softmax + dropout, register-resident (r5, verified): S fp32 -> P bf16.
// ---------------------------------------------------------------------------
__global__ __launch_bounds__(256)
void softmax_dropout(const float* __restrict__ S, bf16_t* __restrict__ P) {
    const unsigned row = blockIdx.x;
    const float* rp = S + (long long)row * LSEQ;
    const int tid = threadIdx.x;

    float v[8];
    *(float4*)(v)     = *(const float4*)(rp + tid * 8);
    *(float4*)(v + 4) = *(const float4*)(rp + tid * 8 + 4);

    float m = v[0];
#pragma unroll
    for (int e = 1; e < 8; ++e) m = fmaxf(m, v[e]);
#pragma unroll
    for (int o = 1; o < 64; o <<= 1) m = fmaxf(m, __shfl_xor(m, o));
    __shared__ float redm[4];
    if ((tid & 63) == 0) redm[tid >> 6] = m;
    __syncthreads();
    m = fmaxf(fmaxf(redm[0], redm[1]), fmaxf(redm[2], redm[3]));

    float s = 0.f;
#pragma unroll
    for (int e = 0; e < 8; ++e) { v[e] = __expf(v[e] - m); s += v[e]; }
#pragma unroll
    for (int o = 1; o < 64; o <<= 1) s += __shfl_xor(s, o);
    __shared__ float reds[4];
    if ((tid & 63) == 0) reds[tid >> 6] = s;
    __syncthreads();
    s = (reds[0] + reds[1]) + (reds[2] + reds[3]);

    const float inv = 2.0f / s;  // dropout /0.5 folded in
    const unsigned nb = row * (unsigned)LSEQ + (unsigned)(tid * 8);
    bf16x8 o8;
#pragma unroll
    for (int e = 0; e < 8; ++e)
        o8[e] = (bf16_t)(dropout_keep(nb + e) ? v[e] * inv : 0.0f);
    *(bf16x8*)(P + (long long)row * LSEQ + tid * 8) = o8;
}

// ---------------------------------------------------------------------------
extern "C" void kernel_launch(void* const* d_in, const int* in_sizes, int n_in,
                              void* d_out, int out_size, void* d_ws, size_t ws_size,
                              hipStream_t stream) {
    const float* query = (const float*)d_in[0];
    const float* key_  = (const float*)d_in[1];
    const float* value = (const float*)d_in[2];
    const float* Wq = (const float*)d_in[3];
    const float* bq = (const float*)d_in[4];
    const float* Wk = (const float*)d_in[5];
    const float* bk = (const float*)d_in[6];
    const float* Wv = (const float*)d_in[7];
    const float* bv = (const float*)d_in[8];
    float* out = (float*)d_out;

    // ws layout (bytes), Q1 = 8192*1024*2 = 16.78MB; total 9*Q1 + 8.4MB = 159.4MB
    char* w = (char*)d_ws;
    const size_t Q1 = (size_t)MROWS * DMODEL * 2;
    bf16_t* Qh  = (bf16_t*)(w);               // [0,2Q1): Qh,Kh  (z-stride NELEM)
    bf16_t* Ql  = (bf16_t*)(w + 2 * Q1);      // [2Q1,4Q1): Ql,Kl
    bf16_t* VT  = (bf16_t*)(w + 4 * Q1);      // [4Q1,5Q1): V^T per batch [D][LK]
    float*  S   = (float*)(w + 5 * Q1);       // [5Q1,9Q1) fp32 scores
    // phase-A aliases inside S region:
    bf16_t* XvH  = (bf16_t*)(w + 5 * Q1);     // V bf16 (hi only)
    bf16_t* XqkH = (bf16_t*)(w + 5 * Q1);     // QK split hi (z-stride NELEM)
    bf16_t* XqkL = (bf16_t*)(w + 7 * Q1);     // QK split lo (z-stride NELEM)
    bf16_t* WTh = (bf16_t*)(w + 9 * Q1);      // 2 z-slots of D*D
    bf16_t* WTl = (bf16_t*)(w + 9 * Q1 + 2 * (size_t)DMODEL * DMODEL * 2);
    bf16_t* P   = Qh;  // [0,2Q1) aliases Qh+Kh (dead after QK^T)

    dim3 b256(256);
    dim3 b512(512);
    const int NELEM = MROWS * DMODEL;
    const long long DD = (long long)DMODEL * DMODEL;
    dim3 gwt1(DMODEL / 32, DMODEL / 32, 1);
    dim3 gwt2(DMODEL / 32, DMODEL / 32, 2);

    // --- V path: V^T = Wv^T @ Xv^T directly (plain bf16, row-bias)
    // grid: NX=LSEQ/128=16, NY=DMODEL/128=8, NZ=4 -> 512 blocks, SX=2
    split_transpose<<<gwt1, b256, 0, stream>>>(Wv, nullptr, WTh, WTl, DMODEL, DMODEL);
    cvt_bf16<<<dim3(NELEM / 2048), b256, 0, stream>>>(value, XvH, NELEM);
    gemm_mfma<0, 2, 1><<<dim3(512), b256, 0, stream>>>(
        WTh, nullptr, XvH, nullptr, bv, nullptr, nullptr, VT, nullptr,
        DMODEL, LSEQ, DMODEL, 1.f,
        0, (long long)LSEQ * DMODEL, (long long)DMODEL * LSEQ,
        2, DMODEL / 128);

    // --- Q and K projections, fused over z (4-phase pipelined 256^2 kernel)
    // grid: NXt=4, NYt=32, NZ=2 -> 256 blocks, 1 block/CU
    split_transpose<<<gwt2, b256, 0, stream>>>(Wq, Wk, WTh, WTl, DMODEL, DMODEL);
    split_f32<<<dim3(NELEM / 1024, 2), b256, 0, stream>>>(query, key_, XqkH, XqkL, NELEM);
    gemm_mfma_8ph<1><<<dim3(256), b512, 0, stream>>>(
        XqkH, XqkL, WTh, WTl, bq, bk, nullptr, Qh, Ql,
        MROWS, DMODEL, DMODEL, 1.f,
        (long long)NELEM, DD, (long long)NELEM,
        MROWS / 256, 2);

    // --- S = 8 * Q K^T (batched, 4-phase pipelined 256^2 kernel)
    // grid: NXt=8, NYt=8, NZ=4 -> 256 blocks, 1 block/CU
    gemm_mfma_8ph<0><<<dim3(256), b512, 0, stream>>>(
        Qh, Ql, Qh + NELEM, Ql + NELEM, nullptr, nullptr, S, nullptr, nullptr,
        LSEQ, LSEQ, DMODEL, SCORE_SCALE,
        (long long)LSEQ * DMODEL, (long long)LSEQ * DMODEL,
        (long long)LSEQ * LSEQ,
        LSEQ / 256, 4);

    // --- softmax + dropout -> P bf16 (aliases Qh/Kh region)
    softmax_dropout<<<dim3(MROWS), b256, 0, stream>>>(S, P);

    // --- O = P V (plain bf16), B operand = V^T [D][LK] per batch
    // grid: NX=8, NY=16, NZ=4 -> 512 blocks, SX=1
    gemm_mfma<0, 0, 0><<<dim3(512), b256, 0, stream>>>(
        P, nullptr, VT, nullptr, nullptr, nullptr, out, nullptr, nullptr,
        LSEQ, DMODEL, LSEQ, 1.f,
        (long long)LSEQ * LSEQ, (long long)DMODEL * LSEQ,
        (long long)LSEQ * DMODEL,
        1, LSEQ / 128);
}

// Round 4
// 437.636 us; speedup vs baseline: 1.0938x; 1.0352x over previous
//
#include <hip/hip_runtime.h>
#include <math.h>

// Problem constants
#define BATCH  4
#define LSEQ   2048
#define DMODEL 1024
#define MROWS  (BATCH * LSEQ)   // 8192
#define SCORE_SCALE 8.0f        // sqrt(1024/16), reference MULTIPLIES

#define THREEFRY_PARTITIONABLE 1  // verified correct in round 1

typedef __bf16 bf16_t;
typedef bf16_t bf16x8 __attribute__((ext_vector_type(8)));
typedef bf16_t bf16x4 __attribute__((ext_vector_type(4)));
typedef float  f32x4  __attribute__((ext_vector_type(4)));

#define LDSP(p) ((__attribute__((address_space(3))) void*)(p))
#define GLBP(p) ((const __attribute__((address_space(1))) void*)(p))

// ---------------------------------------------------------------------------
// threefry dropout (verified round 1)
// ---------------------------------------------------------------------------
__device__ __forceinline__ unsigned rotl32(unsigned x, int r) {
    return (x << r) | (x >> (32 - r));
}

__device__ __forceinline__ void threefry2x32(unsigned k0, unsigned k1,
                                             unsigned x0, unsigned x1,
                                             unsigned& o0, unsigned& o1) {
    const unsigned ks0 = k0, ks1 = k1, ks2 = k0 ^ k1 ^ 0x1BD11BDAu;
    x0 += ks0; x1 += ks1;
#define TF_R(r) { x0 += x1; x1 = rotl32(x1, r); x1 ^= x0; }
    TF_R(13) TF_R(15) TF_R(26) TF_R(6)
    x0 += ks1; x1 += ks2 + 1u;
    TF_R(17) TF_R(29) TF_R(16) TF_R(24)
    x0 += ks2; x1 += ks0 + 2u;
    TF_R(13) TF_R(15) TF_R(26) TF_R(6)
    x0 += ks0; x1 += ks1 + 3u;
    TF_R(17) TF_R(29) TF_R(16) TF_R(24)
    x0 += ks1; x1 += ks2 + 4u;
    TF_R(13) TF_R(15) TF_R(26) TF_R(6)
    x0 += ks2; x1 += ks0 + 5u;
#undef TF_R
    o0 = x0; o1 = x1;
}

__device__ __forceinline__ bool dropout_keep(unsigned n) {
    unsigned o0, o1;
#if THREEFRY_PARTITIONABLE
    threefry2x32(0u, 42u, 0u, n, o0, o1);
    unsigned bits = o0 ^ o1;
#else
    const unsigned HALF = (unsigned)(BATCH * LSEQ) * (unsigned)LSEQ / 2u;
    unsigned c0 = (n < HALF) ? n : (n - HALF);
    unsigned c1 = (n < HALF) ? (n + HALF) : n;
    threefry2x32(0u, 42u, c0, c1, o0, o1);
    unsigned bits = (n < HALF) ? o0 : o1;
#endif
    return bits < 0x80000000u;
}

// ---------------------------------------------------------------------------
// Split fp32 -> bf16 hi/lo. grid.y selects input (X0/X1), output offset y*n.
// ---------------------------------------------------------------------------
__global__ __launch_bounds__(256)
void split_f32(const float* __restrict__ X0, const float* __restrict__ X1,
               bf16_t* __restrict__ hi, bf16_t* __restrict__ lo, int n) {
    const int y = blockIdx.y;
    const float* X = y ? X1 : X0;
    long long i = (long long)(blockIdx.x * 256 + threadIdx.x) * 4;
    if (i >= n) return;
    float4 v = *(const float4*)(X + i);
    bf16x4 h, l;
    h[0] = (bf16_t)v.x; l[0] = (bf16_t)(v.x - (float)h[0]);
    h[1] = (bf16_t)v.y; l[1] = (bf16_t)(v.y - (float)h[1]);
    h[2] = (bf16_t)v.z; l[2] = (bf16_t)(v.z - (float)h[2]);
    h[3] = (bf16_t)v.w; l[3] = (bf16_t)(v.w - (float)h[3]);
    *(bf16x4*)(hi + (long long)y * n + i) = h;
    *(bf16x4*)(lo + (long long)y * n + i) = l;
}

// plain fp32 -> bf16 convert (V path needs only hi plane)
__global__ __launch_bounds__(256)
void cvt_bf16(const float* __restrict__ X, bf16_t* __restrict__ Y, int n) {
    long long i = (long long)(blockIdx.x * 256 + threadIdx.x) * 8;
    if (i >= n) return;
    float4 a = *(const float4*)(X + i);
    float4 b = *(const float4*)(X + i + 4);
    bf16x8 o;
    o[0] = (bf16_t)a.x; o[1] = (bf16_t)a.y; o[2] = (bf16_t)a.z; o[3] = (bf16_t)a.w;
    o[4] = (bf16_t)b.x; o[5] = (bf16_t)b.y; o[6] = (bf16_t)b.z; o[7] = (bf16_t)b.w;
    *(bf16x8*)(Y + i) = o;
}

// W fp32 [K][N] -> W^T hi/lo bf16 [N][K]; grid.z selects W0/W1, out += z*K*N
__global__ __launch_bounds__(256)
void split_transpose(const float* __restrict__ W0, const float* __restrict__ W1,
                     bf16_t* __restrict__ Th, bf16_t* __restrict__ Tl,
                     int Kd, int Nd) {
    __shared__ float t[32][33];
    const int z = blockIdx.z;
    const float* W = z ? W1 : W0;
    const long long zo = (long long)z * Kd * Nd;
    const int bx = blockIdx.x * 32;  // n
    const int by = blockIdx.y * 32;  // k
    const int tx = threadIdx.x & 31, ty = threadIdx.x >> 5;  // 32x8
#pragma unroll
    for (int i = 0; i < 4; ++i)
        t[ty + i * 8][tx] = W[(long long)(by + ty + i * 8) * Nd + bx + tx];
    __syncthreads();
#pragma unroll
    for (int i = 0; i < 4; ++i) {
        float v = t[tx][ty + i * 8];
        long long idx = zo + (long long)(bx + ty + i * 8) * Kd + by + tx;
        bf16_t h = (bf16_t)v;
        Th[idx] = h;
        Tl[idx] = (bf16_t)(v - (float)h);
    }
}

// ---------------------------------------------------------------------------
// MFMA GEMM (128x128, plain bf16 paths: V^T and PV). Unchanged from r5.
// ---------------------------------------------------------------------------
template <int SPLIT, int OUT, int BROW>
__global__ __launch_bounds__(256)
void gemm_mfma(const bf16_t* __restrict__ Ah, const bf16_t* __restrict__ Al,
               const bf16_t* __restrict__ Bh, const bf16_t* __restrict__ Bl,
               const float* __restrict__ bias, const float* __restrict__ bias2,
               float* __restrict__ Cf, bf16_t* __restrict__ Ch,
               bf16_t* __restrict__ Cl,
               int M, int N, int K, float scale,
               long long sA, long long sB, long long sC,
               int SX, int NYt) {
    constexpr int TM = 128, TN = 128, TOT = 256, CHUNKS = 4;
    constexpr int NB = SPLIT ? 2 : 1;
    constexpr int BUFSZ = NB * TOT * 32;
    __shared__ __align__(16) bf16_t smem[2 * BUFSZ];

    // --- XCD-aware tile mapping (1D grid) ---
    const int bid = blockIdx.x;
    const int xcd = bid & 7;
    const int ii = bid >> 3;
    const int perz = SX * NYt;
    const int zz = ii / perz;
    const int rr = ii - zz * perz;
    const int nx = xcd + ((rr % SX) << 3);
    const int my = rr / SX;
    const long long z = zz;
    const int m0 = my * TM, n0 = nx * TN;

    const int tid = threadIdx.x;
    const int lane = tid & 63;
    const int wave = tid >> 6;
    const int quad = lane >> 4;
    const int l16 = lane & 15;
    const int wm = (wave & 1) * 64;
    const int wn = (wave >> 1) * 64;

    const bf16_t* gAh = Ah + z * sA;
    const bf16_t* gBh = Bh + z * sB;
    const bf16_t* gAl = SPLIT ? Al + z * sA : nullptr;
    const bf16_t* gBl = SPLIT ? Bl + z * sB : nullptr;

    // staging lane geometry: 16 rows x 4 column-groups of 16B per chunk
    const int lrow = lane >> 2;                               // 0..15
    const int scol = ((lane & 3) ^ ((lrow >> 1) & 3)) * 8;    // swizzled col
    const int sw = (l16 >> 1) & 3;                            // read swizzle

    auto issue = [&](int k0, int b) {
        bf16_t* base = smem + b * BUFSZ;
#pragma unroll
        for (int c = 0; c < CHUNKS; ++c) {
            const int rbase = wave * 64 + c * 16;
            const int row = rbase + lrow;
            if (rbase < TM) {
                const long long g = (long long)(m0 + row) * K + k0 + scol;
                __builtin_amdgcn_global_load_lds(GLBP(gAh + g), LDSP(base + row * 32), 16, 0, 0);
                if constexpr (SPLIT)
                    __builtin_amdgcn_global_load_lds(GLBP(gAl + g), LDSP(base + TOT * 32 + row * 32), 16, 0, 0);
            } else {
                const int br = row - TM;
                const long long g = (long long)(n0 + br) * K + k0 + scol;
                __builtin_amdgcn_global_load_lds(GLBP(gBh + g), LDSP(base + TM * 32 + br * 32), 16, 0, 0);
                if constexpr (SPLIT)
                    __builtin_amdgcn_global_load_lds(GLBP(gBl + g), LDSP(base + TOT * 32 + TM * 32 + br * 32), 16, 0, 0);
            }
        }
    };

    f32x4 acc[4][4];
#pragma unroll
    for (int i = 0; i < 4; ++i)
#pragma unroll
        for (int j = 0; j < 4; ++j)
            acc[i][j] = (f32x4){0.f, 0.f, 0.f, 0.f};

    issue(0, 0);
    const int NIT = K >> 5;
    for (int it = 0; it < NIT; ++it) {
        const int b = it & 1;
        const bool more = (it + 1) < NIT;
        if (more) issue((it + 1) << 5, b ^ 1);
        if constexpr (SPLIT) {
            if (more) asm volatile("s_waitcnt vmcnt(8)" ::: "memory");
            else      asm volatile("s_waitcnt vmcnt(0)" ::: "memory");
        } else {
            if (more) asm volatile("s_waitcnt vmcnt(4)" ::: "memory");
            else      asm volatile("s_waitcnt vmcnt(0)" ::: "memory");
        }
        asm volatile("s_barrier" ::: "memory");

        bf16_t* base = smem + b * BUFSZ;
        bf16_t* sAh = base;
        bf16_t* sBh = base + TM * 32;
        bf16_t* sAl = base + TOT * 32;
        bf16_t* sBl = base + TOT * 32 + TM * 32;

        bf16x8 afh[4], bfh[4], afl[4], bfl[4];
#pragma unroll
        for (int i = 0; i < 4; ++i) {
            const int ao = (wm + i * 16 + l16) * 32 + (quad ^ sw) * 8;
            afh[i] = *(const bf16x8*)(sAh + ao);
            if constexpr (SPLIT) afl[i] = *(const bf16x8*)(sAl + ao);
        }
#pragma unroll
        for (int j = 0; j < 4; ++j) {
            const int bo = (wn + j * 16 + l16) * 32 + (quad ^ sw) * 8;
            bfh[j] = *(const bf16x8*)(sBh + bo);
            if constexpr (SPLIT) bfl[j] = *(const bf16x8*)(sBl + bo);
        }
#pragma unroll
        for (int i = 0; i < 4; ++i)
#pragma unroll
            for (int j = 0; j < 4; ++j) {
                acc[i][j] = __builtin_amdgcn_mfma_f32_16x16x32_bf16(afh[i], bfh[j], acc[i][j], 0, 0, 0);
                if constexpr (SPLIT) {
                    acc[i][j] = __builtin_amdgcn_mfma_f32_16x16x32_bf16(afh[i], bfl[j], acc[i][j], 0, 0, 0);
                    acc[i][j] = __builtin_amdgcn_mfma_f32_16x16x32_bf16(afl[i], bfh[j], acc[i][j], 0, 0, 0);
                }
            }
        asm volatile("s_barrier" ::: "memory");
    }

    const float* bz = (z == 1 && bias2) ? bias2 : bias;
#pragma unroll
    for (int i = 0; i < 4; ++i)
#pragma unroll
        for (int j = 0; j < 4; ++j) {
            const int n = n0 + wn + j * 16 + l16;
            float bvn = 0.f;
            if constexpr (OUT != 0 && !BROW) bvn = bz[n];
#pragma unroll
            for (int r = 0; r < 4; ++r) {
                const int m = m0 + wm + i * 16 + quad * 4 + r;
                const long long idx = z * sC + (long long)m * N + n;
                float v = acc[i][j][r];
                if constexpr (OUT == 0) {
                    Cf[idx] = v * scale;
                } else if constexpr (OUT == 1) {
                    v += bvn;
                    bf16_t h = (bf16_t)v;
                    Ch[idx] = h;
                    Cl[idx] = (bf16_t)(v - (float)h);
                } else {
                    v += BROW ? bz[m] : bvn;
                    Ch[idx] = (bf16_t)v;
                }
            }
        }
}

// ---------------------------------------------------------------------------
// r9: 256x256-tile split GEMM — read-ahead pipeline, ONE barrier per phase.
// 512 threads (8 waves, 2Mx4N), BK=32, per-wave output 128x64 (acc[8][4]).
// LDS planes: 0=Ah 1=Al 2=Bh 3=Bl, each 256x32 bf16 (16KB); x2 buffers = 128KB.
//
// Key change vs r8 (43% MfmaUtil, ~970 dead cycles/phase): every register
// operand is ds_read ONE FULL PHASE before its MFMA uses it, so no lgkmcnt(0)
// stall and only ONE barrier per phase (4/K-tile vs 8).
//   - A-frags ping-pong 2 slots: phase p MFMAs slot p&1, reads slot (p+1)&1.
//     ph3 reads next tile's A0 (pre-MFMA) and B frags (post-MFMA, reg reuse).
//   - Staging rounds (r0,r1=Bh; r2,r3=Bl; r4+p=A-pair p) spread 3/2/2/1:
//     ph0:{r0,r1,r2} ph1:{r3,r4} ph2:{r5,r6} ph3:{r7}.
//   - Derived gates (vmcnt BEFORE the barrier; FIFO-verified, prologue acts
//     as pseudo-ph3): steady {ph0:4, ph1:5, ph2:2, ph3:2}; tail {1,0,-,-}.
//     Every gated load is >=1.3 phases old -> ~no stall; 2-6 always in flight.
//   - No explicit lgkmcnt: C++ ds_reads consumed a phase later; compiler
//     inserts counted waits with a phase+barrier of slack.
//   - K-loop 2x-unrolled so buffer parity is compile-time (rule #20).
// Same verified XOR col-group swizzle -> 0 bank conflicts.
// Grid: 256 blocks, 1 block/CU, XCD-contiguous mapping (nx slowest).
// OUT: 0 = fp32*scale (S=QK^T), 1 = bf16 hi/lo + bias (projections, bias2=z1).
// ---------------------------------------------------------------------------
template <int OUT>
__global__ __launch_bounds__(512, 2)
void gemm_mfma_8ph(const bf16_t* __restrict__ Ah, const bf16_t* __restrict__ Al,
                   const bf16_t* __restrict__ Bh, const bf16_t* __restrict__ Bl,
                   const float* __restrict__ bias, const float* __restrict__ bias2,
                   float* __restrict__ Cf, bf16_t* __restrict__ Ch,
                   bf16_t* __restrict__ Cl,
                   int M, int N, int K, float scale,
                   long long sA, long long sB, long long sC,
                   int NYt, int NZ) {
    constexpr int TM = 256, TN = 256;
    constexpr int PLANE = 256 * 32;               // elements per plane (16 KB)
    constexpr int HB = 4 * PLANE;                 // half (one buffer) = 64 KB
    __shared__ __align__(16) bf16_t smem[2 * HB]; // 128 KB

    // --- XCD-contiguous tile mapping: gid ordered (nx, z, my), nx slowest ---
    const int bid = blockIdx.x;
    const int gid = (bid & 7) * 32 + (bid >> 3);   // 256 blocks total
    const int nzy = NZ * NYt;
    const int nx = gid / nzy;
    const int rem = gid - nx * nzy;
    const int zz = rem / NYt;
    const int my = rem - zz * NYt;
    const long long z = zz;
    const int m0 = my * TM, n0 = nx * TN;

    const int tid = threadIdx.x;
    const int lane = tid & 63;
    const int wave = tid >> 6;          // 0..7
    const int quad = lane >> 4;
    const int l16 = lane & 15;
    const int wm = (wave >> 2) * 128;   // 0,128
    const int wn = (wave & 3) * 64;     // 0,64,128,192

    const bf16_t* gAh = Ah + z * sA;
    const bf16_t* gAl = Al + z * sA;
    const bf16_t* gBh = Bh + z * sB;
    const bf16_t* gBl = Bl + z * sB;

    // staging lane geometry (verified swizzle: key = row % 16)
    const int lrow = lane >> 2;                               // 0..15
    const int scol = ((lane & 3) ^ ((lrow >> 1) & 3)) * 8;    // swizzled col
    const int sw = (l16 >> 1) & 3;                            // read swizzle

    // stage one round r (0..7) of K-tile at k0 into buffer base (1 issue/wave)
    auto stage_round = [&](int r, int k0, bf16_t* base) {
        if (r < 4) {
            // B planes: r0 Bh rows 0-127, r1 Bh 128-255, r2 Bl 0-127, r3 Bl 128-255
            const int row = ((r & 1) << 7) + (wave << 4) + lrow;
            const bf16_t* src = (r >= 2) ? gBl : gBh;
            bf16_t* dst = base + ((r >= 2) ? 3 : 2) * PLANE + row * 32;
            __builtin_amdgcn_global_load_lds(
                GLBP(src + (long long)(n0 + row) * K + k0 + scol), LDSP(dst), 16, 0, 0);
        } else {
            // A pair for phase p: waves 0-3 -> Ah, 4-7 -> Al; rows {32p, 128+32p}
            const int p = r - 4;
            const int row = (p << 5) + ((wave & 2) ? 128 : 0) + ((wave & 1) << 4) + lrow;
            const bf16_t* src = (wave >= 4) ? gAl : gAh;
            bf16_t* dst = base + ((wave >= 4) ? 1 : 0) * PLANE + row * 32;
            __builtin_amdgcn_global_load_lds(
                GLBP(src + (long long)(m0 + row) * K + k0 + scol), LDSP(dst), 16, 0, 0);
        }
    };

    f32x4 acc[8][4];
#pragma unroll
    for (int i = 0; i < 8; ++i)
#pragma unroll
        for (int j = 0; j < 4; ++j)
            acc[i][j] = (f32x4){0.f, 0.f, 0.f, 0.f};

    bf16x8 ah[2][2], al[2][2];   // A frag slots (ping-pong by phase parity)
    bf16x8 bfh[4], bfl[4];       // B frags for current tile

    // --- prologue: stage full tile 0 into buf0; gate r0..r5 landed; then
    //     read A0(t0)->slot0 and B(t0) (acts as pseudo-ph3 of it=-1). ---
#pragma unroll
    for (int r = 0; r < 8; ++r) stage_round(r, 0, smem);
    asm volatile("s_waitcnt vmcnt(2)" ::: "memory");
    asm volatile("s_barrier" ::: "memory");
    __builtin_amdgcn_sched_barrier(0);
#pragma unroll
    for (int i = 0; i < 2; ++i) {
        const int ao = (wm + i * 16 + l16) * 32 + (quad ^ sw) * 8;
        ah[0][i] = *(const bf16x8*)(smem + ao);
        al[0][i] = *(const bf16x8*)(smem + PLANE + ao);
    }
#pragma unroll
    for (int j = 0; j < 4; ++j) {
        const int bo = (wn + j * 16 + l16) * 32 + (quad ^ sw) * 8;
        bfh[j] = *(const bf16x8*)(smem + 2 * PLANE + bo);
        bfl[j] = *(const bf16x8*)(smem + 3 * PLANE + bo);
    }

    const int NIT = K >> 5;   // 32 (even)
    for (int itp = 0; itp < NIT; itp += 2) {
#pragma unroll
        for (int h = 0; h < 2; ++h) {
            const int it = itp + h;
            const bool more = (it + 1) < NIT;
            const int k1 = (it + 1) << 5;
            bf16_t* cur = smem + h * HB;          // tile it (compile-time base)
            bf16_t* nxt = smem + (h ^ 1) * HB;    // tile it+1
#pragma unroll
            for (int ph = 0; ph < 4; ++ph) {
                // --- 1. read-ahead A frags for next phase ---
                if (ph < 3) {
#pragma unroll
                    for (int i = 0; i < 2; ++i) {
                        const int ao = (wm + ((ph + 1) * 2 + i) * 16 + l16) * 32 + (quad ^ sw) * 8;
                        ah[(ph + 1) & 1][i] = *(const bf16x8*)(cur + ao);
                        al[(ph + 1) & 1][i] = *(const bf16x8*)(cur + PLANE + ao);
                    }
                } else if (more) {
                    // A0 of next tile -> slot0 (visibility: ph2-end gate)
#pragma unroll
                    for (int i = 0; i < 2; ++i) {
                        const int ao = (wm + i * 16 + l16) * 32 + (quad ^ sw) * 8;
                        ah[0][i] = *(const bf16x8*)(nxt + ao);
                        al[0][i] = *(const bf16x8*)(nxt + PLANE + ao);
                    }
                }
                // --- 2. stage rounds of next tile (3/2/2/1) ---
                if (more) {
                    if (ph == 0)      { stage_round(0, k1, nxt); stage_round(1, k1, nxt); stage_round(2, k1, nxt); }
                    else if (ph == 1) { stage_round(3, k1, nxt); stage_round(4, k1, nxt); }
                    else if (ph == 2) { stage_round(5, k1, nxt); stage_round(6, k1, nxt); }
                    else              { stage_round(7, k1, nxt); }
                }
                // --- 3. MFMA cluster on current slot (loaded last phase) ---
                __builtin_amdgcn_s_setprio(1);
#pragma unroll
                for (int i = 0; i < 2; ++i)
#pragma unroll
                    for (int j = 0; j < 4; ++j) {
                        f32x4 a = acc[ph * 2 + i][j];
                        a = __builtin_amdgcn_mfma_f32_16x16x32_bf16(ah[ph & 1][i], bfh[j], a, 0, 0, 0);
                        a = __builtin_amdgcn_mfma_f32_16x16x32_bf16(ah[ph & 1][i], bfl[j], a, 0, 0, 0);
                        a = __builtin_amdgcn_mfma_f32_16x16x32_bf16(al[ph & 1][i], bfh[j], a, 0, 0, 0);
                        acc[ph * 2 + i][j] = a;
                    }
                __builtin_amdgcn_s_setprio(0);
                // --- 4. ph3: B frags of next tile (after last use of old B) ---
                if (ph == 3 && more) {
#pragma unroll
                    for (int j = 0; j < 4; ++j) {
                        const int bo = (wn + j * 16 + l16) * 32 + (quad ^ sw) * 8;
                        bfh[j] = *(const bf16x8*)(nxt + 2 * PLANE + bo);
                        bfl[j] = *(const bf16x8*)(nxt + 3 * PLANE + bo);
                    }
                }
                // --- 5. derived vmcnt gate + single barrier ---
                if (more) {
                    if (ph == 0)      asm volatile("s_waitcnt vmcnt(4)" ::: "memory");
                    else if (ph == 1) asm volatile("s_waitcnt vmcnt(5)" ::: "memory");
                    else              asm volatile("s_waitcnt vmcnt(2)" ::: "memory");
                    asm volatile("s_barrier" ::: "memory");
                    __builtin_amdgcn_sched_barrier(0);
                } else {
                    if (ph == 0) {
                        asm volatile("s_waitcnt vmcnt(1)" ::: "memory");
                        asm volatile("s_barrier" ::: "memory");
                        __builtin_amdgcn_sched_barrier(0);
                    } else if (ph == 1) {
                        asm volatile("s_waitcnt vmcnt(0)" ::: "memory");
                        asm volatile("s_barrier" ::: "memory");
                        __builtin_amdgcn_sched_barrier(0);
                    }
                    // ph2/ph3 tail: no cross-wave deps remain; no gate/barrier
                }
            }
        }
    }

    const float* bz = (z == 1 && bias2) ? bias2 : bias;
#pragma unroll
    for (int i = 0; i < 8; ++i)
#pragma unroll
        for (int j = 0; j < 4; ++j) {
            const int n = n0 + wn + j * 16 + l16;
            float bvn = 0.f;
            if constexpr (OUT != 0) bvn = bz[n];
#pragma unroll
            for (int r = 0; r < 4; ++r) {
                const int m = m0 + wm + i * 16 + quad * 4 + r;
                const long long idx = z * sC + (long long)m * N + n;
                float v = acc[i][j][r];
                if constexpr (OUT == 0) {
                    Cf[idx] = v * scale;
                } else {
                    v += bvn;
                    bf16_t h = (bf16_t)v;
                    Ch[idx] = h;
                    Cl[idx] = (bf16_t)(v - (float)h);
                }
            }
        }
}

// ---------------------------------------------------------------------------
// Row softmax + dropout, register-resident (r5, verified): S fp32 -> P bf16.
// ---------------------------------------------------------------------------
__global__ __launch_bounds__(256)
void softmax_dropout(const float* __restrict__ S, bf16_t* __restrict__ P) {
    const unsigned row = blockIdx.x;
    const float* rp = S + (long long)row * LSEQ;
    const int tid = threadIdx.x;

    float v[8];
    *(float4*)(v)     = *(const float4*)(rp + tid * 8);
    *(float4*)(v + 4) = *(const float4*)(rp + tid * 8 + 4);

    float m = v[0];
#pragma unroll
    for (int e = 1; e < 8; ++e) m = fmaxf(m, v[e]);
#pragma unroll
    for (int o = 1; o < 64; o <<= 1) m = fmaxf(m, __shfl_xor(m, o));
    __shared__ float redm[4];
    if ((tid & 63) == 0) redm[tid >> 6] = m;
    __syncthreads();
    m = fmaxf(fmaxf(redm[0], redm[1]), fmaxf(redm[2], redm[3]));

    float s = 0.f;
#pragma unroll
    for (int e = 0; e < 8; ++e) { v[e] = __expf(v[e] - m); s += v[e]; }
#pragma unroll
    for (int o = 1; o < 64; o <<= 1) s += __shfl_xor(s, o);
    __shared__ float reds[4];
    if ((tid & 63) == 0) reds[tid >> 6] = s;
    __syncthreads();
    s = (reds[0] + reds[1]) + (reds[2] + reds[3]);

    const float inv = 2.0f / s;  // dropout /0.5 folded in
    const unsigned nb = row * (unsigned)LSEQ + (unsigned)(tid * 8);
    bf16x8 o8;
#pragma unroll
    for (int e = 0; e < 8; ++e)
        o8[e] = (bf16_t)(dropout_keep(nb + e) ? v[e] * inv : 0.0f);
    *(bf16x8*)(P + (long long)row * LSEQ + tid * 8) = o8;
}

// ---------------------------------------------------------------------------
extern "C" void kernel_launch(void* const* d_in, const int* in_sizes, int n_in,
                              void* d_out, int out_size, void* d_ws, size_t ws_size,
                              hipStream_t stream) {
    const float* query = (const float*)d_in[0];
    const float* key_  = (const float*)d_in[1];
    const float* value = (const float*)d_in[2];
    const float* Wq = (const float*)d_in[3];
    const float* bq = (const float*)d_in[4];
    const float* Wk = (const float*)d_in[5];
    const float* bk = (const float*)d_in[6];
    const float* Wv = (const float*)d_in[7];
    const float* bv = (const float*)d_in[8];
    float* out = (float*)d_out;

    // ws layout (bytes), Q1 = 8192*1024*2 = 16.78MB; total 9*Q1 + 8.4MB = 159.4MB
    char* w = (char*)d_ws;
    const size_t Q1 = (size_t)MROWS * DMODEL * 2;
    bf16_t* Qh  = (bf16_t*)(w);               // [0,2Q1): Qh,Kh  (z-stride NELEM)
    bf16_t* Ql  = (bf16_t*)(w + 2 * Q1);      // [2Q1,4Q1): Ql,Kl
    bf16_t* VT  = (bf16_t*)(w + 4 * Q1);      // [4Q1,5Q1): V^T per batch [D][LK]
    float*  S   = (float*)(w + 5 * Q1);       // [5Q1,9Q1) fp32 scores
    // phase-A aliases inside S region:
    bf16_t* XvH  = (bf16_t*)(w + 5 * Q1);     // V bf16 (hi only)
    bf16_t* XqkH = (bf16_t*)(w + 5 * Q1);     // QK split hi (z-stride NELEM)
    bf16_t* XqkL = (bf16_t*)(w + 7 * Q1);     // QK split lo (z-stride NELEM)
    bf16_t* WTh = (bf16_t*)(w + 9 * Q1);      // 2 z-slots of D*D
    bf16_t* WTl = (bf16_t*)(w + 9 * Q1 + 2 * (size_t)DMODEL * DMODEL * 2);
    bf16_t* P   = Qh;  // [0,2Q1) aliases Qh+Kh (dead after QK^T)

    dim3 b256(256);
    dim3 b512(512);
    const int NELEM = MROWS * DMODEL;
    const long long DD = (long long)DMODEL * DMODEL;
    dim3 gwt1(DMODEL / 32, DMODEL / 32, 1);
    dim3 gwt2(DMODEL / 32, DMODEL / 32, 2);

    // --- V path: V^T = Wv^T @ Xv^T directly (plain bf16, row-bias)
    // grid: NX=LSEQ/128=16, NY=DMODEL/128=8, NZ=4 -> 512 blocks, SX=2
    split_transpose<<<gwt1, b256, 0, stream>>>(Wv, nullptr, WTh, WTl, DMODEL, DMODEL);
    cvt_bf16<<<dim3(NELEM / 2048), b256, 0, stream>>>(value, XvH, NELEM);
    gemm_mfma<0, 2, 1><<<dim3(512), b256, 0, stream>>>(
        WTh, nullptr, XvH, nullptr, bv, nullptr, nullptr, VT, nullptr,
        DMODEL, LSEQ, DMODEL, 1.f,
        0, (long long)LSEQ * DMODEL, (long long)DMODEL * LSEQ,
        2, DMODEL / 128);

    // --- Q and K projections, fused over z (read-ahead pipelined 256^2 kernel)
    // grid: NXt=4, NYt=32, NZ=2 -> 256 blocks, 1 block/CU
    split_transpose<<<gwt2, b256, 0, stream>>>(Wq, Wk, WTh, WTl, DMODEL, DMODEL);
    split_f32<<<dim3(NELEM / 1024, 2), b256, 0, stream>>>(query, key_, XqkH, XqkL, NELEM);
    gemm_mfma_8ph<1><<<dim3(256), b512, 0, stream>>>(
        XqkH, XqkL, WTh, WTl, bq, bk, nullptr, Qh, Ql,
        MROWS, DMODEL, DMODEL, 1.f,
        (long long)NELEM, DD, (long long)NELEM,
        MROWS / 256, 2);

    // --- S = 8 * Q K^T (batched, read-ahead pipelined 256^2 kernel)
    // grid: NXt=8, NYt=8, NZ=4 -> 256 blocks, 1 block/CU
    gemm_mfma_8ph<0><<<dim3(256), b512, 0, stream>>>(
        Qh, Ql, Qh + NELEM, Ql + NELEM, nullptr, nullptr, S, nullptr, nullptr,
        LSEQ, LSEQ, DMODEL, SCORE_SCALE,
        (long long)LSEQ * DMODEL, (long long)LSEQ * DMODEL,
        (long long)LSEQ * LSEQ,
        LSEQ / 256, 4);

    // --- softmax + dropout -> P bf16 (aliases Qh/Kh region)
    softmax_dropout<<<dim3(MROWS), b256, 0, stream>>>(S, P);

    // --- O = P V (plain bf16), B operand = V^T [D][LK] per batch
    // grid: NX=8, NY=16, NZ=4 -> 512 blocks, SX=1
    gemm_mfma<0, 0, 0><<<dim3(512), b256, 0, stream>>>(
        P, nullptr, VT, nullptr, nullptr, nullptr, out, nullptr, nullptr,
        LSEQ, DMODEL, LSEQ, 1.f,
        (long long)LSEQ * LSEQ, (long long)DMODEL * LSEQ,
        (long long)LSEQ * DMODEL,
        1, LSEQ / 128);
}

// Round 5
// 425.148 us; speedup vs baseline: 1.1259x; 1.0294x over previous
//
#include <hip/hip_runtime.h>
#include <math.h>

// Problem constants
#define BATCH  4
#define LSEQ   2048
#define DMODEL 1024
#define MROWS  (BATCH * LSEQ)   // 8192
#define SCORE_SCALE 8.0f        // sqrt(1024/16), reference MULTIPLIES

#define THREEFRY_PARTITIONABLE 1  // verified correct in round 1

typedef __bf16 bf16_t;
typedef bf16_t bf16x8 __attribute__((ext_vector_type(8)));
typedef bf16_t bf16x4 __attribute__((ext_vector_type(4)));
typedef float  f32x4  __attribute__((ext_vector_type(4)));

#define LDSP(p) ((__attribute__((address_space(3))) void*)(p))
#define GLBP(p) ((const __attribute__((address_space(1))) void*)(p))

// ---------------------------------------------------------------------------
// threefry dropout (verified round 1)
// ---------------------------------------------------------------------------
__device__ __forceinline__ unsigned rotl32(unsigned x, int r) {
    return (x << r) | (x >> (32 - r));
}

__device__ __forceinline__ void threefry2x32(unsigned k0, unsigned k1,
                                             unsigned x0, unsigned x1,
                                             unsigned& o0, unsigned& o1) {
    const unsigned ks0 = k0, ks1 = k1, ks2 = k0 ^ k1 ^ 0x1BD11BDAu;
    x0 += ks0; x1 += ks1;
#define TF_R(r) { x0 += x1; x1 = rotl32(x1, r); x1 ^= x0; }
    TF_R(13) TF_R(15) TF_R(26) TF_R(6)
    x0 += ks1; x1 += ks2 + 1u;
    TF_R(17) TF_R(29) TF_R(16) TF_R(24)
    x0 += ks2; x1 += ks0 + 2u;
    TF_R(13) TF_R(15) TF_R(26) TF_R(6)
    x0 += ks0; x1 += ks1 + 3u;
    TF_R(17) TF_R(29) TF_R(16) TF_R(24)
    x0 += ks1; x1 += ks2 + 4u;
    TF_R(13) TF_R(15) TF_R(26) TF_R(6)
    x0 += ks2; x1 += ks0 + 5u;
#undef TF_R
    o0 = x0; o1 = x1;
}

__device__ __forceinline__ bool dropout_keep(unsigned n) {
    unsigned o0, o1;
#if THREEFRY_PARTITIONABLE
    threefry2x32(0u, 42u, 0u, n, o0, o1);
    unsigned bits = o0 ^ o1;
#else
    const unsigned HALF = (unsigned)(BATCH * LSEQ) * (unsigned)LSEQ / 2u;
    unsigned c0 = (n < HALF) ? n : (n - HALF);
    unsigned c1 = (n < HALF) ? (n + HALF) : n;
    threefry2x32(0u, 42u, c0, c1, o0, o1);
    unsigned bits = (n < HALF) ? o0 : o1;
#endif
    return bits < 0x80000000u;
}

// ---------------------------------------------------------------------------
// Split fp32 -> bf16 hi/lo. grid.y selects input (X0/X1), output offset y*n.
// ---------------------------------------------------------------------------
__global__ __launch_bounds__(256)
void split_f32(const float* __restrict__ X0, const float* __restrict__ X1,
               bf16_t* __restrict__ hi, bf16_t* __restrict__ lo, int n) {
    const int y = blockIdx.y;
    const float* X = y ? X1 : X0;
    long long i = (long long)(blockIdx.x * 256 + threadIdx.x) * 4;
    if (i >= n) return;
    float4 v = *(const float4*)(X + i);
    bf16x4 h, l;
    h[0] = (bf16_t)v.x; l[0] = (bf16_t)(v.x - (float)h[0]);
    h[1] = (bf16_t)v.y; l[1] = (bf16_t)(v.y - (float)h[1]);
    h[2] = (bf16_t)v.z; l[2] = (bf16_t)(v.z - (float)h[2]);
    h[3] = (bf16_t)v.w; l[3] = (bf16_t)(v.w - (float)h[3]);
    *(bf16x4*)(hi + (long long)y * n + i) = h;
    *(bf16x4*)(lo + (long long)y * n + i) = l;
}

// plain fp32 -> bf16 convert (V path needs only hi plane)
__global__ __launch_bounds__(256)
void cvt_bf16(const float* __restrict__ X, bf16_t* __restrict__ Y, int n) {
    long long i = (long long)(blockIdx.x * 256 + threadIdx.x) * 8;
    if (i >= n) return;
    float4 a = *(const float4*)(X + i);
    float4 b = *(const float4*)(X + i + 4);
    bf16x8 o;
    o[0] = (bf16_t)a.x; o[1] = (bf16_t)a.y; o[2] = (bf16_t)a.z; o[3] = (bf16_t)a.w;
    o[4] = (bf16_t)b.x; o[5] = (bf16_t)b.y; o[6] = (bf16_t)b.z; o[7] = (bf16_t)b.w;
    *(bf16x8*)(Y + i) = o;
}

// W fp32 [K][N] -> W^T hi/lo bf16 [N][K]; grid.z selects W0/W1, out += z*K*N
__global__ __launch_bounds__(256)
void split_transpose(const float* __restrict__ W0, const float* __restrict__ W1,
                     bf16_t* __restrict__ Th, bf16_t* __restrict__ Tl,
                     int Kd, int Nd) {
    __shared__ float t[32][33];
    const int z = blockIdx.z;
    const float* W = z ? W1 : W0;
    const long long zo = (long long)z * Kd * Nd;
    const int bx = blockIdx.x * 32;  // n
    const int by = blockIdx.y * 32;  // k
    const int tx = threadIdx.x & 31, ty = threadIdx.x >> 5;  // 32x8
#pragma unroll
    for (int i = 0; i < 4; ++i)
        t[ty + i * 8][tx] = W[(long long)(by + ty + i * 8) * Nd + bx + tx];
    __syncthreads();
#pragma unroll
    for (int i = 0; i < 4; ++i) {
        float v = t[tx][ty + i * 8];
        long long idx = zo + (long long)(bx + ty + i * 8) * Kd + by + tx;
        bf16_t h = (bf16_t)v;
        Th[idx] = h;
        Tl[idx] = (bf16_t)(v - (float)h);
    }
}

// ---------------------------------------------------------------------------
// r10: gemm_pipe — plain-bf16 pipelined GEMM for V^T and PV paths.
// TM=128 x TN=256, BK=32, 512 threads (8 waves 2Mx4N), wave tile 64x64,
// acc[4][4]. ONE phase per K-tile (16 MFMA/wave). TRIPLE-buffered LDS
// (3 x 24KB = 72KB): phase t stages tile t+3 into the buffer tile t just
// vacated (t's frags already in regs); frags of tile t+1 are ds_read during
// phase t (register slots ping-pong by t&1, compile-time via macro).
// Gates (FIFO-verified): prologue stages t0,t1,t2 (9 loads), vmcnt(3)
// (t0,t1 landed); steady gate vmcnt(3) at phase end ensures tile t+2 landed
// (loads >=1.3 phases old); tail t=NIT-3 -> vmcnt(0); no barrier after
// t=NIT-3. lgkmcnt(0) before each barrier: every wave drains its own frag
// reads before crossing -> staging into the just-read buffer is WAR-safe.
// Same verified XOR col-group swizzle (0 bank conflicts).
// Grid: exactly 256 blocks, 1 block/CU, XCD mapping (nx slowest).
// OUT: 0 = fp32*scale, 2 = bf16 + row-bias (bias[m]).
// ---------------------------------------------------------------------------
template <int OUT>
__global__ __launch_bounds__(512, 2)
void gemm_pipe(const bf16_t* __restrict__ A, const bf16_t* __restrict__ B,
               const float* __restrict__ bias,
               float* __restrict__ Cf, bf16_t* __restrict__ Ch,
               int M, int N, int K, float scale,
               long long sA, long long sB, long long sC,
               int NYt, int NZ) {
    constexpr int ABUF = 128 * 32;                 // A plane elements (8 KB)
    constexpr int BUFE = ABUF + 256 * 32;          // one buffer = 12288 elem (24 KB)
    __shared__ __align__(16) bf16_t smem[3 * BUFE];  // 72 KB

    // --- XCD mapping: gid ordered (nx, z, my), nx slowest ---
    const int bid = blockIdx.x;
    const int gid = (bid & 7) * 32 + (bid >> 3);   // 256 blocks
    const int nzy = NZ * NYt;
    const int nx = gid / nzy;
    const int rem = gid - nx * nzy;
    const int zz = rem / NYt;
    const int my = rem - zz * NYt;
    const long long z = zz;
    const int m0 = my * 128, n0 = nx * 256;

    const int tid = threadIdx.x;
    const int lane = tid & 63;
    const int wave = tid >> 6;          // 0..7
    const int quad = lane >> 4;
    const int l16 = lane & 15;
    const int wm = (wave >> 2) * 64;    // 0,64
    const int wn = (wave & 3) * 64;     // 0,64,128,192

    const bf16_t* gA = A + z * sA;
    const bf16_t* gB = B + z * sB;

    // staging lane geometry (verified swizzle: key = row % 16)
    const int lrow = lane >> 2;                               // 0..15
    const int scol = ((lane & 3) ^ ((lrow >> 1) & 3)) * 8;    // swizzled col
    const int sw = (l16 >> 1) & 3;                            // read swizzle

    // stage one K-tile (3 global_load_lds per wave: A 128 rows, B 256 rows)
    auto stage_tile = [&](int k0, bf16_t* base) {
        {
            const int row = (wave << 4) + lrow;
            __builtin_amdgcn_global_load_lds(
                GLBP(gA + (long long)(m0 + row) * K + k0 + scol),
                LDSP(base + row * 32), 16, 0, 0);
        }
#pragma unroll
        for (int r = 0; r < 2; ++r) {
            const int row = (r << 7) + (wave << 4) + lrow;
            __builtin_amdgcn_global_load_lds(
                GLBP(gB + (long long)(n0 + row) * K + k0 + scol),
                LDSP(base + ABUF + row * 32), 16, 0, 0);
        }
    };

    f32x4 acc[4][4];
#pragma unroll
    for (int i = 0; i < 4; ++i)
#pragma unroll
        for (int j = 0; j < 4; ++j)
            acc[i][j] = (f32x4){0.f, 0.f, 0.f, 0.f};

    bf16x8 fa0[4], fb0[4], fa1[4], fb1[4];   // frag slots (ping-pong by t&1)

    const int NIT = K >> 5;   // 32 or 64 (even, >= 8)

    bf16_t* p0 = smem;             // buf[t%3]   (current tile; staging target)
    bf16_t* p1 = smem + BUFE;      // buf[(t+1)%3] (read source for frags t+1)
    bf16_t* p2 = smem + 2 * BUFE;  // buf[(t+2)%3]

    // prologue: stage tiles 0,1,2; make t0,t1 visible; read frags(t0)->slot0
    stage_tile(0, p0);
    stage_tile(32, p1);
    stage_tile(64, p2);
    asm volatile("s_waitcnt vmcnt(3)" ::: "memory");
    asm volatile("s_barrier" ::: "memory");
    __builtin_amdgcn_sched_barrier(0);
#pragma unroll
    for (int i = 0; i < 4; ++i) {
        const int ao = (wm + i * 16 + l16) * 32 + (quad ^ sw) * 8;
        fa0[i] = *(const bf16x8*)(p0 + ao);
    }
#pragma unroll
    for (int j = 0; j < 4; ++j) {
        const int bo = ABUF + (wn + j * 16 + l16) * 32 + (quad ^ sw) * 8;
        fb0[j] = *(const bf16x8*)(p0 + bo);
    }

#define PIPE_ITER(T, FAc, FBc, FAn, FBn)                                      \
    {                                                                         \
        const int t_ = (T);                                                   \
        if (t_ + 1 < NIT) {                                                   \
            _Pragma("unroll")                                                 \
            for (int i = 0; i < 4; ++i) {                                     \
                const int ao = (wm + i * 16 + l16) * 32 + (quad ^ sw) * 8;    \
                FAn[i] = *(const bf16x8*)(p1 + ao);                           \
            }                                                                 \
            _Pragma("unroll")                                                 \
            for (int j = 0; j < 4; ++j) {                                     \
                const int bo = ABUF + (wn + j * 16 + l16) * 32 + (quad ^ sw) * 8; \
                FBn[j] = *(const bf16x8*)(p1 + bo);                           \
            }                                                                 \
        }                                                                     \
        if (t_ + 3 < NIT) stage_tile((t_ + 3) << 5, p0);                      \
        __builtin_amdgcn_s_setprio(1);                                        \
        _Pragma("unroll")                                                     \
        for (int i = 0; i < 4; ++i)                                           \
            _Pragma("unroll")                                                 \
            for (int j = 0; j < 4; ++j)                                       \
                acc[i][j] = __builtin_amdgcn_mfma_f32_16x16x32_bf16(          \
                    FAc[i], FBc[j], acc[i][j], 0, 0, 0);                      \
        __builtin_amdgcn_s_setprio(0);                                        \
        if (t_ + 2 < NIT) {                                                   \
            asm volatile("s_waitcnt lgkmcnt(0)" ::: "memory");                \
            if (t_ + 3 < NIT) asm volatile("s_waitcnt vmcnt(3)" ::: "memory");\
            else              asm volatile("s_waitcnt vmcnt(0)" ::: "memory");\
            asm volatile("s_barrier" ::: "memory");                           \
            __builtin_amdgcn_sched_barrier(0);                                \
        }                                                                     \
        { bf16_t* tmp_ = p0; p0 = p1; p1 = p2; p2 = tmp_; }                   \
    }

    for (int tp = 0; tp < NIT; tp += 2) {
        PIPE_ITER(tp,     fa0, fb0, fa1, fb1)
        PIPE_ITER(tp + 1, fa1, fb1, fa0, fb0)
    }
#undef PIPE_ITER

    // epilogue (per-wave private output region; no barrier needed)
#pragma unroll
    for (int i = 0; i < 4; ++i)
#pragma unroll
        for (int j = 0; j < 4; ++j) {
            const int n = n0 + wn + j * 16 + l16;
#pragma unroll
            for (int r = 0; r < 4; ++r) {
                const int m = m0 + wm + i * 16 + quad * 4 + r;
                const long long idx = z * sC + (long long)m * N + n;
                float v = acc[i][j][r];
                if constexpr (OUT == 0) {
                    Cf[idx] = v * scale;
                } else {
                    Ch[idx] = (bf16_t)(v + bias[m]);
                }
            }
        }
}

// ---------------------------------------------------------------------------
// r9 split kernel (unchanged): 256x256-tile split GEMM — read-ahead pipeline,
// one barrier per phase. See r9 notes. Verified: 94.8us, MfmaUtil 47.5%.
// ---------------------------------------------------------------------------
template <int OUT>
__global__ __launch_bounds__(512, 2)
void gemm_mfma_8ph(const bf16_t* __restrict__ Ah, const bf16_t* __restrict__ Al,
                   const bf16_t* __restrict__ Bh, const bf16_t* __restrict__ Bl,
                   const float* __restrict__ bias, const float* __restrict__ bias2,
                   float* __restrict__ Cf, bf16_t* __restrict__ Ch,
                   bf16_t* __restrict__ Cl,
                   int M, int N, int K, float scale,
                   long long sA, long long sB, long long sC,
                   int NYt, int NZ) {
    constexpr int TM = 256, TN = 256;
    constexpr int PLANE = 256 * 32;               // elements per plane (16 KB)
    constexpr int HB = 4 * PLANE;                 // half (one buffer) = 64 KB
    __shared__ __align__(16) bf16_t smem[2 * HB]; // 128 KB

    // --- XCD-contiguous tile mapping: gid ordered (nx, z, my), nx slowest ---
    const int bid = blockIdx.x;
    const int gid = (bid & 7) * 32 + (bid >> 3);   // 256 blocks total
    const int nzy = NZ * NYt;
    const int nx = gid / nzy;
    const int rem = gid - nx * nzy;
    const int zz = rem / NYt;
    const int my = rem - zz * NYt;
    const long long z = zz;
    const int m0 = my * TM, n0 = nx * TN;

    const int tid = threadIdx.x;
    const int lane = tid & 63;
    const int wave = tid >> 6;          // 0..7
    const int quad = lane >> 4;
    const int l16 = lane & 15;
    const int wm = (wave >> 2) * 128;   // 0,128
    const int wn = (wave & 3) * 64;     // 0,64,128,192

    const bf16_t* gAh = Ah + z * sA;
    const bf16_t* gAl = Al + z * sA;
    const bf16_t* gBh = Bh + z * sB;
    const bf16_t* gBl = Bl + z * sB;

    // staging lane geometry (verified swizzle: key = row % 16)
    const int lrow = lane >> 2;                               // 0..15
    const int scol = ((lane & 3) ^ ((lrow >> 1) & 3)) * 8;    // swizzled col
    const int sw = (l16 >> 1) & 3;                            // read swizzle

    // stage one round r (0..7) of K-tile at k0 into buffer base (1 issue/wave)
    auto stage_round = [&](int r, int k0, bf16_t* base) {
        if (r < 4) {
            // B planes: r0 Bh rows 0-127, r1 Bh 128-255, r2 Bl 0-127, r3 Bl 128-255
            const int row = ((r & 1) << 7) + (wave << 4) + lrow;
            const bf16_t* src = (r >= 2) ? gBl : gBh;
            bf16_t* dst = base + ((r >= 2) ? 3 : 2) * PLANE + row * 32;
            __builtin_amdgcn_global_load_lds(
                GLBP(src + (long long)(n0 + row) * K + k0 + scol), LDSP(dst), 16, 0, 0);
        } else {
            // A pair for phase p: waves 0-3 -> Ah, 4-7 -> Al; rows {32p, 128+32p}
            const int p = r - 4;
            const int row = (p << 5) + ((wave & 2) ? 128 : 0) + ((wave & 1) << 4) + lrow;
            const bf16_t* src = (wave >= 4) ? gAl : gAh;
            bf16_t* dst = base + ((wave >= 4) ? 1 : 0) * PLANE + row * 32;
            __builtin_amdgcn_global_load_lds(
                GLBP(src + (long long)(m0 + row) * K + k0 + scol), LDSP(dst), 16, 0, 0);
        }
    };

    f32x4 acc[8][4];
#pragma unroll
    for (int i = 0; i < 8; ++i)
#pragma unroll
        for (int j = 0; j < 4; ++j)
            acc[i][j] = (f32x4){0.f, 0.f, 0.f, 0.f};

    bf16x8 ah[2][2], al[2][2];   // A frag slots (ping-pong by phase parity)
    bf16x8 bfh[4], bfl[4];       // B frags for current tile

    // --- prologue: stage full tile 0 into buf0; gate r0..r5 landed; then
    //     read A0(t0)->slot0 and B(t0) (acts as pseudo-ph3 of it=-1). ---
#pragma unroll
    for (int r = 0; r < 8; ++r) stage_round(r, 0, smem);
    asm volatile("s_waitcnt vmcnt(2)" ::: "memory");
    asm volatile("s_barrier" ::: "memory");
    __builtin_amdgcn_sched_barrier(0);
#pragma unroll
    for (int i = 0; i < 2; ++i) {
        const int ao = (wm + i * 16 + l16) * 32 + (quad ^ sw) * 8;
        ah[0][i] = *(const bf16x8*)(smem + ao);
        al[0][i] = *(const bf16x8*)(smem + PLANE + ao);
    }
#pragma unroll
    for (int j = 0; j < 4; ++j) {
        const int bo = (wn + j * 16 + l16) * 32 + (quad ^ sw) * 8;
        bfh[j] = *(const bf16x8*)(smem + 2 * PLANE + bo);
        bfl[j] = *(const bf16x8*)(smem + 3 * PLANE + bo);
    }

    const int NIT = K >> 5;   // 32 (even)
    for (int itp = 0; itp < NIT; itp += 2) {
#pragma unroll
        for (int h = 0; h < 2; ++h) {
            const int it = itp + h;
            const bool more = (it + 1) < NIT;
            const int k1 = (it + 1) << 5;
            bf16_t* cur = smem + h * HB;          // tile it (compile-time base)
            bf16_t* nxt = smem + (h ^ 1) * HB;    // tile it+1
#pragma unroll
            for (int ph = 0; ph < 4; ++ph) {
                // --- 1. read-ahead A frags for next phase ---
                if (ph < 3) {
#pragma unroll
                    for (int i = 0; i < 2; ++i) {
                        const int ao = (wm + ((ph + 1) * 2 + i) * 16 + l16) * 32 + (quad ^ sw) * 8;
                        ah[(ph + 1) & 1][i] = *(const bf16x8*)(cur + ao);
                        al[(ph + 1) & 1][i] = *(const bf16x8*)(cur + PLANE + ao);
                    }
                } else if (more) {
                    // A0 of next tile -> slot0 (visibility: ph2-end gate)
#pragma unroll
                    for (int i = 0; i < 2; ++i) {
                        const int ao = (wm + i * 16 + l16) * 32 + (quad ^ sw) * 8;
                        ah[0][i] = *(const bf16x8*)(nxt + ao);
                        al[0][i] = *(const bf16x8*)(nxt + PLANE + ao);
                    }
                }
                // --- 2. stage rounds of next tile (3/2/2/1) ---
                if (more) {
                    if (ph == 0)      { stage_round(0, k1, nxt); stage_round(1, k1, nxt); stage_round(2, k1, nxt); }
                    else if (ph == 1) { stage_round(3, k1, nxt); stage_round(4, k1, nxt); }
                    else if (ph == 2) { stage_round(5, k1, nxt); stage_round(6, k1, nxt); }
                    else              { stage_round(7, k1, nxt); }
                }
                // --- 3. MFMA cluster on current slot (loaded last phase) ---
                __builtin_amdgcn_s_setprio(1);
#pragma unroll
                for (int i = 0; i < 2; ++i)
#pragma unroll
                    for (int j = 0; j < 4; ++j) {
                        f32x4 a = acc[ph * 2 + i][j];
                        a = __builtin_amdgcn_mfma_f32_16x16x32_bf16(ah[ph & 1][i], bfh[j], a, 0, 0, 0);
                        a = __builtin_amdgcn_mfma_f32_16x16x32_bf16(ah[ph & 1][i], bfl[j], a, 0, 0, 0);
                        a = __builtin_amdgcn_mfma_f32_16x16x32_bf16(al[ph & 1][i], bfh[j], a, 0, 0, 0);
                        acc[ph * 2 + i][j] = a;
                    }
                __builtin_amdgcn_s_setprio(0);
                // --- 4. ph3: B frags of next tile (after last use of old B) ---
                if (ph == 3 && more) {
#pragma unroll
                    for (int j = 0; j < 4; ++j) {
                        const int bo = (wn + j * 16 + l16) * 32 + (quad ^ sw) * 8;
                        bfh[j] = *(const bf16x8*)(nxt + 2 * PLANE + bo);
                        bfl[j] = *(const bf16x8*)(nxt + 3 * PLANE + bo);
                    }
                }
                // --- 5. derived vmcnt gate + single barrier ---
                if (more) {
                    if (ph == 0)      asm volatile("s_waitcnt vmcnt(4)" ::: "memory");
                    else if (ph == 1) asm volatile("s_waitcnt vmcnt(5)" ::: "memory");
                    else              asm volatile("s_waitcnt vmcnt(2)" ::: "memory");
                    asm volatile("s_barrier" ::: "memory");
                    __builtin_amdgcn_sched_barrier(0);
                } else {
                    if (ph == 0) {
                        asm volatile("s_waitcnt vmcnt(1)" ::: "memory");
                        asm volatile("s_barrier" ::: "memory");
                        __builtin_amdgcn_sched_barrier(0);
                    } else if (ph == 1) {
                        asm volatile("s_waitcnt vmcnt(0)" ::: "memory");
                        asm volatile("s_barrier" ::: "memory");
                        __builtin_amdgcn_sched_barrier(0);
                    }
                    // ph2/ph3 tail: no cross-wave deps remain; no gate/barrier
                }
            }
        }
    }

    const float* bz = (z == 1 && bias2) ? bias2 : bias;
#pragma unroll
    for (int i = 0; i < 8; ++i)
#pragma unroll
        for (int j = 0; j < 4; ++j) {
            const int n = n0 + wn + j * 16 + l16;
            float bvn = 0.f;
            if constexpr (OUT != 0) bvn = bz[n];
#pragma unroll
            for (int r = 0; r < 4; ++r) {
                const int m = m0 + wm + i * 16 + quad * 4 + r;
                const long long idx = z * sC + (long long)m * N + n;
                float v = acc[i][j][r];
                if constexpr (OUT == 0) {
                    Cf[idx] = v * scale;
                } else {
                    v += bvn;
                    bf16_t h = (bf16_t)v;
                    Ch[idx] = h;
                    Cl[idx] = (bf16_t)(v - (float)h);
                }
            }
        }
}

// ---------------------------------------------------------------------------
// Row softmax + dropout, register-resident (r5, verified): S fp32 -> P bf16.
// ---------------------------------------------------------------------------
__global__ __launch_bounds__(256)
void softmax_dropout(const float* __restrict__ S, bf16_t* __restrict__ P) {
    const unsigned row = blockIdx.x;
    const float* rp = S + (long long)row * LSEQ;
    const int tid = threadIdx.x;

    float v[8];
    *(float4*)(v)     = *(const float4*)(rp + tid * 8);
    *(float4*)(v + 4) = *(const float4*)(rp + tid * 8 + 4);

    float m = v[0];
#pragma unroll
    for (int e = 1; e < 8; ++e) m = fmaxf(m, v[e]);
#pragma unroll
    for (int o = 1; o < 64; o <<= 1) m = fmaxf(m, __shfl_xor(m, o));
    __shared__ float redm[4];
    if ((tid & 63) == 0) redm[tid >> 6] = m;
    __syncthreads();
    m = fmaxf(fmaxf(redm[0], redm[1]), fmaxf(redm[2], redm[3]));

    float s = 0.f;
#pragma unroll
    for (int e = 0; e < 8; ++e) { v[e] = __expf(v[e] - m); s += v[e]; }
#pragma unroll
    for (int o = 1; o < 64; o <<= 1) s += __shfl_xor(s, o);
    __shared__ float reds[4];
    if ((tid & 63) == 0) reds[tid >> 6] = s;
    __syncthreads();
    s = (reds[0] + reds[1]) + (reds[2] + reds[3]);

    const float inv = 2.0f / s;  // dropout /0.5 folded in
    const unsigned nb = row * (unsigned)LSEQ + (unsigned)(tid * 8);
    bf16x8 o8;
#pragma unroll
    for (int e = 0; e < 8; ++e)
        o8[e] = (bf16_t)(dropout_keep(nb + e) ? v[e] * inv : 0.0f);
    *(bf16x8*)(P + (long long)row * LSEQ + tid * 8) = o8;
}

// ---------------------------------------------------------------------------
extern "C" void kernel_launch(void* const* d_in, const int* in_sizes, int n_in,
                              void* d_out, int out_size, void* d_ws, size_t ws_size,
                              hipStream_t stream) {
    const float* query = (const float*)d_in[0];
    const float* key_  = (const float*)d_in[1];
    const float* value = (const float*)d_in[2];
    const float* Wq = (const float*)d_in[3];
    const float* bq = (const float*)d_in[4];
    const float* Wk = (const float*)d_in[5];
    const float* bk = (const float*)d_in[6];
    const float* Wv = (const float*)d_in[7];
    const float* bv = (const float*)d_in[8];
    float* out = (float*)d_out;

    // ws layout (bytes), Q1 = 8192*1024*2 = 16.78MB; total 9*Q1 + 8.4MB = 159.4MB
    char* w = (char*)d_ws;
    const size_t Q1 = (size_t)MROWS * DMODEL * 2;
    bf16_t* Qh  = (bf16_t*)(w);               // [0,2Q1): Qh,Kh  (z-stride NELEM)
    bf16_t* Ql  = (bf16_t*)(w + 2 * Q1);      // [2Q1,4Q1): Ql,Kl
    bf16_t* VT  = (bf16_t*)(w + 4 * Q1);      // [4Q1,5Q1): V^T per batch [D][LK]
    float*  S   = (float*)(w + 5 * Q1);       // [5Q1,9Q1) fp32 scores
    // phase-A aliases inside S region:
    bf16_t* XvH  = (bf16_t*)(w + 5 * Q1);     // V bf16 (hi only)
    bf16_t* XqkH = (bf16_t*)(w + 5 * Q1);     // QK split hi (z-stride NELEM)
    bf16_t* XqkL = (bf16_t*)(w + 7 * Q1);     // QK split lo (z-stride NELEM)
    bf16_t* WTh = (bf16_t*)(w + 9 * Q1);      // 2 z-slots of D*D
    bf16_t* WTl = (bf16_t*)(w + 9 * Q1 + 2 * (size_t)DMODEL * DMODEL * 2);
    bf16_t* P   = Qh;  // [0,2Q1) aliases Qh+Kh (dead after QK^T)

    dim3 b256(256);
    dim3 b512(512);
    const int NELEM = MROWS * DMODEL;
    const long long DD = (long long)DMODEL * DMODEL;
    dim3 gwt1(DMODEL / 32, DMODEL / 32, 1);
    dim3 gwt2(DMODEL / 32, DMODEL / 32, 2);

    // --- V path: V^T = Wv^T @ Xv^T (pipelined plain kernel, row-bias)
    // TM=128 (D), TN=256 (LSEQ): NYt=8, NXt=8, NZ=4 -> 256 blocks, 1/CU
    split_transpose<<<gwt1, b256, 0, stream>>>(Wv, nullptr, WTh, WTl, DMODEL, DMODEL);
    cvt_bf16<<<dim3(NELEM / 2048), b256, 0, stream>>>(value, XvH, NELEM);
    gemm_pipe<2><<<dim3(256), b512, 0, stream>>>(
        WTh, XvH, bv, nullptr, VT,
        DMODEL, LSEQ, DMODEL, 1.f,
        0, (long long)LSEQ * DMODEL, (long long)DMODEL * LSEQ,
        DMODEL / 128, 4);

    // --- Q and K projections, fused over z (read-ahead pipelined 256^2 kernel)
    // grid: NXt=4, NYt=32, NZ=2 -> 256 blocks, 1 block/CU
    split_transpose<<<gwt2, b256, 0, stream>>>(Wq, Wk, WTh, WTl, DMODEL, DMODEL);
    split_f32<<<dim3(NELEM / 1024, 2), b256, 0, stream>>>(query, key_, XqkH, XqkL, NELEM);
    gemm_mfma_8ph<1><<<dim3(256), b512, 0, stream>>>(
        XqkH, XqkL, WTh, WTl, bq, bk, nullptr, Qh, Ql,
        MROWS, DMODEL, DMODEL, 1.f,
        (long long)NELEM, DD, (long long)NELEM,
        MROWS / 256, 2);

    // --- S = 8 * Q K^T (batched, read-ahead pipelined 256^2 kernel)
    // grid: NXt=8, NYt=8, NZ=4 -> 256 blocks, 1 block/CU
    gemm_mfma_8ph<0><<<dim3(256), b512, 0, stream>>>(
        Qh, Ql, Qh + NELEM, Ql + NELEM, nullptr, nullptr, S, nullptr, nullptr,
        LSEQ, LSEQ, DMODEL, SCORE_SCALE,
        (long long)LSEQ * DMODEL, (long long)LSEQ * DMODEL,
        (long long)LSEQ * LSEQ,
        LSEQ / 256, 4);

    // --- softmax + dropout -> P bf16 (aliases Qh/Kh region)
    softmax_dropout<<<dim3(MROWS), b256, 0, stream>>>(S, P);

    // --- O = P V (pipelined plain kernel), B operand = V^T [D][LK] per batch
    // TM=128 (LSEQ), TN=256 (D): NYt=16, NXt=4, NZ=4 -> 256 blocks, 1/CU
    gemm_pipe<0><<<dim3(256), b512, 0, stream>>>(
        P, VT, nullptr, out, nullptr,
        LSEQ, DMODEL, LSEQ, 1.f,
        (long long)LSEQ * LSEQ, (long long)DMODEL * LSEQ, (long long)LSEQ * DMODEL,
        LSEQ / 128, 4);
}